// Round 1
// baseline (1439.438 us; speedup 1.0000x reference)
//
#include <hip/hip_runtime.h>

// SOMNetwork forward, fp32. Pipeline per channel c in {0,1,2}:
//   L1: 5x5/s4 rbf-conv (6x6x100) -> std over (B,100) per window pos -> exp/crelu -> 2x2 alpha-pool -> x2 (B*9,100)
//   L2: cdist(x2, w2) (B*9,225) -> global std -> exp/crelu -> 1x3 alpha-pool -> x3 (B*3,225)
//   L3: cdist(x3, w3) (B*3,625) -> global std -> exp/crelu -> 3x1 alpha-pool -> x4 (B,625)
//   L4: cdist(x4, w4) (B,1225)  -> global std -> exp/crelu -> y4; out += y4 @ fcw_c^T  (+fcb on c==0)
// std accumulation: double striped accumulators (zeroed per channel), finalize kernels compute
// sqrt((sumsq - sum^2/n)/(n-1)).

#define STRIPES 64
#define ACC_L1 0              // 36 pos * 64 stripes * 2
#define ACC_L2 4608
#define ACC_L3 4736
#define ACC_L4 4864
#define ACC_TOTAL 5120

__global__ void zero_acc_kernel(double* __restrict__ acc) {
  int i = blockIdx.x * blockDim.x + threadIdx.x;
  if (i < ACC_TOTAL) acc[i] = 0.0;
}

// ---------------- Layer 1: direct squared-distance over 5x5 patches ----------------
__global__ __launch_bounds__(128) void l1_dist_kernel(
    const float* __restrict__ x, int c, const float* __restrict__ w1c,
    float* __restrict__ dist1)
{
  __shared__ float img[784];
  __shared__ float wf[2500];
  int n = blockIdx.x, t = threadIdx.x;
  const float* xim = x + ((size_t)n * 3 + c) * 784;
  for (int i = t; i < 784; i += 128) img[i] = xim[i];
  for (int i = t; i < 2500; i += 128) wf[i] = w1c[i];
  __syncthreads();
  for (int idx = t; idx < 3600; idx += 128) {
    int pos = idx / 100, o = idx - pos * 100;
    int i = pos / 6, j = pos - i * 6;
    const float* p0 = &img[(i * 4) * 28 + (j * 4)];
    const float* w0 = &wf[o * 25];
    float d2 = 0.f;
#pragma unroll
    for (int r = 0; r < 5; ++r)
#pragma unroll
      for (int s = 0; s < 5; ++s) {
        float dd = p0[r * 28 + s] - w0[r * 5 + s];
        d2 = fmaf(dd, dd, d2);
      }
    dist1[((size_t)n * 36 + pos) * 100 + o] = sqrtf(d2 + 1e-12f);
  }
}

// per-window-position sum/sumsq over (B,100)
__global__ __launch_bounds__(128) void l1_reduce_kernel(
    const float* __restrict__ dist1, int B, double* __restrict__ acc)
{
  int pos = blockIdx.x;      // 36
  int stripe = blockIdx.y;   // 64
  int t = threadIdx.x;       // 128 (100 active)
  double s = 0.0, q = 0.0;
  if (t < 100) {
    for (int n = stripe; n < B; n += STRIPES) {
      float d = dist1[((size_t)n * 36 + pos) * 100 + t];
      s += d; q += (double)d * d;
    }
  }
  for (int off = 32; off; off >>= 1) {
    s += __shfl_down(s, off, 64);
    q += __shfl_down(q, off, 64);
  }
  __shared__ double sh[4];
  int wave = t >> 6;
  if ((t & 63) == 0) { sh[wave * 2] = s; sh[wave * 2 + 1] = q; }
  __syncthreads();
  if (t == 0) {
    s = sh[0] + sh[2]; q = sh[1] + sh[3];
    acc[ACC_L1 + (pos * STRIPES + stripe) * 2] = s;      // unique slot per block
    acc[ACC_L1 + (pos * STRIPES + stripe) * 2 + 1] = q;
  }
}

__global__ void l1_fin_kernel(const double* __restrict__ acc, float* __restrict__ stds, double n) {
  int t = threadIdx.x;
  if (t < 36) {
    double s = 0.0, q = 0.0;
    for (int i = 0; i < STRIPES; ++i) {
      s += acc[ACC_L1 + (t * STRIPES + i) * 2];
      q += acc[ACC_L1 + (t * STRIPES + i) * 2 + 1];
    }
    double var = (q - s * s / n) / (n - 1.0);
    stds[t] = (float)sqrt(var > 0.0 ? var : 0.0);
  }
}

// exp -> crelu(cb0) -> 2x2 alpha pool -> x2 (B*9, 100)
__global__ __launch_bounds__(128) void l1_sfm_kernel(
    const float* __restrict__ dist1, const float* __restrict__ stds,
    const float* __restrict__ cb, float* __restrict__ x2)
{
  int b = blockIdx.x, IJ = blockIdx.y;
  int I = IJ / 3, J = IJ - I * 3;
  int ch = threadIdx.x;
  if (ch >= 100) return;
  float bias = cb[0];
  const float A[2][2] = {{0.729f, 0.81f}, {0.9f, 1.0f}};
  float accv = 0.f;
#pragma unroll
  for (int di = 0; di < 2; ++di)
#pragma unroll
    for (int dj = 0; dj < 2; ++dj) {
      int pos = (2 * I + di) * 6 + (2 * J + dj);
      float d = dist1[((size_t)b * 36 + pos) * 100 + ch];
      float tt = d / stds[pos];
      float v = expf(-0.5f * tt * tt);
      v = (v >= bias) ? v : 0.f;
      accv = fmaf(v, A[di][dj], accv);
    }
  x2[((size_t)b * 9 + IJ) * 100 + ch] = accv * 0.25f;
}

// ---------------- generic row squared-norm ----------------
__global__ __launch_bounds__(64) void rownorm_kernel(
    const float* __restrict__ v, int K, float* __restrict__ out)
{
  int r = blockIdx.x, t = threadIdx.x;
  float s = 0.f;
  for (int k = t; k < K; k += 64) { float a = v[(size_t)r * K + k]; s = fmaf(a, a, s); }
  for (int off = 32; off; off >>= 1) s += __shfl_down(s, off, 64);
  if (t == 0) out[r] = s;
}

// ---------------- tiled cdist GEMM: dist[m,o] = sqrt(max(xn+wn-2*x.w,0)+eps) ----------------
// 64x64 tile, BK=16, 256 threads, 4x4 microtile. M must be a multiple of 64.
__global__ __launch_bounds__(256) void gemm_dist_kernel(
    const float* __restrict__ X, const float* __restrict__ W,
    const float* __restrict__ xn, const float* __restrict__ wn,
    float* __restrict__ dist, int O, int K,
    double* __restrict__ acc, int accbase)
{
  __shared__ __align__(16) float Xs[16][68];
  __shared__ __align__(16) float Ws[16][68];
  int m0 = blockIdx.x * 64, o0 = blockIdx.y * 64;
  int t = threadIdx.x;
  int tx = t & 15, ty = t >> 4;
  float accv[4][4] = {{0.f}};
  for (int k0 = 0; k0 < K; k0 += 16) {
#pragma unroll
    for (int e = 0; e < 4; ++e) {
      int idx = t + 256 * e;
      int mi = idx >> 4, ki = idx & 15;
      int k = k0 + ki;
      Xs[ki][mi] = (k < K) ? X[(size_t)(m0 + mi) * K + k] : 0.f;
      int o = o0 + mi;
      Ws[ki][mi] = (k < K && o < O) ? W[(size_t)o * K + k] : 0.f;
    }
    __syncthreads();
#pragma unroll
    for (int ki = 0; ki < 16; ++ki) {
      float4 xv = *(const float4*)&Xs[ki][ty * 4];
      float4 wv = *(const float4*)&Ws[ki][tx * 4];
      float xa[4] = {xv.x, xv.y, xv.z, xv.w};
      float wa[4] = {wv.x, wv.y, wv.z, wv.w};
#pragma unroll
      for (int r = 0; r < 4; ++r)
#pragma unroll
        for (int cc = 0; cc < 4; ++cc)
          accv[r][cc] = fmaf(xa[r], wa[cc], accv[r][cc]);
    }
    __syncthreads();
  }
  double s = 0.0, q = 0.0;
#pragma unroll
  for (int r = 0; r < 4; ++r) {
    int m = m0 + ty * 4 + r;
    float xnv = xn[m];
#pragma unroll
    for (int cc = 0; cc < 4; ++cc) {
      int o = o0 + tx * 4 + cc;
      if (o < O) {
        float d2 = xnv + wn[o] - 2.f * accv[r][cc];
        float d = sqrtf(fmaxf(d2, 0.f) + 1e-12f);
        dist[(size_t)m * O + o] = d;
        s += d; q += (double)d * d;
      }
    }
  }
  for (int off = 32; off; off >>= 1) {
    s += __shfl_down(s, off, 64);
    q += __shfl_down(q, off, 64);
  }
  if ((t & 63) == 0) {
    int stripe = (blockIdx.x + blockIdx.y * gridDim.x) & (STRIPES - 1);
    atomicAdd(&acc[accbase + stripe * 2], s);
    atomicAdd(&acc[accbase + stripe * 2 + 1], q);
  }
}

__global__ void gen_fin_kernel(const double* __restrict__ acc, int base, double n,
                               float* __restrict__ stds, int slot)
{
  int t = threadIdx.x;  // 64
  double s = acc[base + t * 2], q = acc[base + t * 2 + 1];
  for (int off = 32; off; off >>= 1) {
    s += __shfl_down(s, off, 64);
    q += __shfl_down(q, off, 64);
  }
  if (t == 0) {
    double var = (q - s * s / n) / (n - 1.0);
    stds[slot] = (float)sqrt(var > 0.0 ? var : 0.0);
  }
}

// exp -> crelu(cb1) -> [0.81,0.9,1]/3 pool over v -> x3 (B*3, 225)
__global__ __launch_bounds__(256) void l2_sfm_kernel(
    const float* __restrict__ dist2, const float* __restrict__ stds,
    const float* __restrict__ cb, float* __restrict__ x3)
{
  int b = blockIdx.x, u = blockIdx.y, ch = threadIdx.x;
  if (ch >= 225) return;
  float sd = stds[36], bias = cb[1];
  const float av[3] = {0.81f, 0.9f, 1.0f};
  float accv = 0.f;
#pragma unroll
  for (int v = 0; v < 3; ++v) {
    float d = dist2[((size_t)b * 9 + u * 3 + v) * 225 + ch];
    float tt = d / sd;
    float val = expf(-0.5f * tt * tt);
    val = (val >= bias) ? val : 0.f;
    accv = fmaf(val, av[v], accv);
  }
  x3[((size_t)b * 3 + u) * 225 + ch] = accv / 3.f;
}

// exp -> crelu(cb2) -> [0.81,0.9,1]/3 pool over u -> x4 (B, 625)
__global__ __launch_bounds__(256) void l3_sfm_kernel(
    const float* __restrict__ dist3, const float* __restrict__ stds,
    const float* __restrict__ cb, float* __restrict__ x4)
{
  int b = blockIdx.x, t = threadIdx.x;
  float sd = stds[37], bias = cb[2];
  const float au[3] = {0.81f, 0.9f, 1.0f};
  for (int ch = t; ch < 625; ch += 256) {
    float accv = 0.f;
#pragma unroll
    for (int u = 0; u < 3; ++u) {
      float d = dist3[((size_t)b * 3 + u) * 625 + ch];
      float tt = d / sd;
      float val = expf(-0.5f * tt * tt);
      val = (val >= bias) ? val : 0.f;
      accv = fmaf(val, au[u], accv);
    }
    x4[(size_t)b * 625 + ch] = accv / 3.f;
  }
}

// exp -> crelu(cb3) -> y4 (B, 1225)
__global__ __launch_bounds__(256) void l4_rbf_kernel(
    const float* __restrict__ dist4, const float* __restrict__ stds,
    const float* __restrict__ cb, float* __restrict__ y4)
{
  int b = blockIdx.x;
  int o = blockIdx.y * 256 + threadIdx.x;
  if (o >= 1225) return;
  float sd = stds[38], bias = cb[3];
  float d = dist4[(size_t)b * 1225 + o];
  float tt = d / sd;
  float val = expf(-0.5f * tt * tt);
  y4[(size_t)b * 1225 + o] = (val >= bias) ? val : 0.f;
}

// out[b,:] (+)= y4[b,:] @ fcw[:, c*1225 : (c+1)*1225]^T  (+ fcb on c==0)
__global__ __launch_bounds__(128) void fc_acc_kernel(
    const float* __restrict__ y4, const float* __restrict__ fcw,
    const float* __restrict__ fcb, float* __restrict__ out, int c)
{
  int b = blockIdx.x, t = threadIdx.x;
  float p[10];
#pragma unroll
  for (int k = 0; k < 10; ++k) p[k] = 0.f;
  for (int j = t; j < 1225; j += 128) {
    float f = y4[(size_t)b * 1225 + j];
#pragma unroll
    for (int k = 0; k < 10; ++k) p[k] = fmaf(f, fcw[k * 3675 + c * 1225 + j], p[k]);
  }
#pragma unroll
  for (int k = 0; k < 10; ++k)
    for (int off = 32; off; off >>= 1) p[k] += __shfl_down(p[k], off, 64);
  __shared__ float red[2][10];
  int wave = t >> 6;
  if ((t & 63) == 0) {
#pragma unroll
    for (int k = 0; k < 10; ++k) red[wave][k] = p[k];
  }
  __syncthreads();
  if (t < 10) {
    float v = red[0][t] + red[1][t];
    if (c == 0) out[(size_t)b * 10 + t] = fcb[t] + v;
    else        out[(size_t)b * 10 + t] += v;
  }
}

extern "C" void kernel_launch(void* const* d_in, const int* in_sizes, int n_in,
                              void* d_out, int out_size, void* d_ws, size_t ws_size,
                              hipStream_t stream) {
  const float* x   = (const float*)d_in[0];
  const float* w1  = (const float*)d_in[1];
  const float* w2  = (const float*)d_in[2];
  const float* w3  = (const float*)d_in[3];
  const float* w4  = (const float*)d_in[4];
  const float* fcw = (const float*)d_in[5];
  const float* fcb = (const float*)d_in[6];
  const float* cb  = (const float*)d_in[7];
  float* out = (float*)d_out;
  int B = in_sizes[0] / (3 * 28 * 28);   // 4096; multiple of 64 assumed

  // workspace layout (floats)
  float* ws   = (float*)d_ws;
  float* bufA = ws;                                  // dist buffers, B*3600 floats (max)
  float* bufB = ws + (size_t)B * 3600;               // x2/x3/x4/y4, B*1225 floats (max)
  float* xn   = bufB + (size_t)B * 1225;             // row norms, up to B*9
  float* wn   = xn + (size_t)B * 9;                  // up to 1225 (+pad)
  float* stds = wn + 1280;                           // 64 floats: [0..35]=L1, 36=L2, 37=L3, 38=L4
  double* acc = (double*)(stds + 64);                // ACC_TOTAL doubles (offset is 8B-aligned)

  int M2 = B * 9, M3 = B * 3;

  for (int c = 0; c < 3; ++c) {
    const float* w2c = w2 + (size_t)c * 225 * 100;
    const float* w3c = w3 + (size_t)c * 625 * 225;
    const float* w4c = w4 + (size_t)c * 1225 * 625;

    zero_acc_kernel<<<(ACC_TOTAL + 255) / 256, 256, 0, stream>>>(acc);

    // Layer 1
    l1_dist_kernel<<<B, 128, 0, stream>>>(x, c, w1 + (size_t)c * 2500, bufA);
    l1_reduce_kernel<<<dim3(36, STRIPES), 128, 0, stream>>>(bufA, B, acc);
    l1_fin_kernel<<<1, 64, 0, stream>>>(acc, stds, (double)B * 100.0);
    l1_sfm_kernel<<<dim3(B, 9), 128, 0, stream>>>(bufA, stds, cb, bufB);

    // Layer 2: X=x2 (M2 x 100), W=(225 x 100)
    rownorm_kernel<<<M2, 64, 0, stream>>>(bufB, 100, xn);
    rownorm_kernel<<<225, 64, 0, stream>>>(w2c, 100, wn);
    gemm_dist_kernel<<<dim3(M2 / 64, 4), 256, 0, stream>>>(bufB, w2c, xn, wn, bufA, 225, 100, acc, ACC_L2);
    gen_fin_kernel<<<1, 64, 0, stream>>>(acc, ACC_L2, (double)M2 * 225.0, stds, 36);
    l2_sfm_kernel<<<dim3(B, 3), 256, 0, stream>>>(bufA, stds, cb, bufB);

    // Layer 3: X=x3 (M3 x 225), W=(625 x 225)
    rownorm_kernel<<<M3, 64, 0, stream>>>(bufB, 225, xn);
    rownorm_kernel<<<625, 64, 0, stream>>>(w3c, 225, wn);
    gemm_dist_kernel<<<dim3(M3 / 64, 10), 256, 0, stream>>>(bufB, w3c, xn, wn, bufA, 625, 225, acc, ACC_L3);
    gen_fin_kernel<<<1, 64, 0, stream>>>(acc, ACC_L3, (double)M3 * 625.0, stds, 37);
    l3_sfm_kernel<<<B, 256, 0, stream>>>(bufA, stds, cb, bufB);

    // Layer 4: X=x4 (B x 625), W=(1225 x 625)
    rownorm_kernel<<<B, 64, 0, stream>>>(bufB, 625, xn);
    rownorm_kernel<<<1225, 64, 0, stream>>>(w4c, 625, wn);
    gemm_dist_kernel<<<dim3(B / 64, 20), 256, 0, stream>>>(bufB, w4c, xn, wn, bufA, 1225, 625, acc, ACC_L4);
    gen_fin_kernel<<<1, 64, 0, stream>>>(acc, ACC_L4, (double)B * 1225.0, stds, 38);
    l4_rbf_kernel<<<dim3(B, 5), 256, 0, stream>>>(bufA, stds, cb, bufB);

    fc_acc_kernel<<<B, 128, 0, stream>>>(bufB, fcw, fcb, out, c);
  }
}

// Round 2
// 1053.335 us; speedup vs baseline: 1.3666x; 1.3666x over previous
//
#include <hip/hip_runtime.h>

// SOMNetwork forward. Per channel: L1 direct rbf-conv (std fused, dist recomputed in sfm),
// L2/L3/L4 cdist via split-bf16 MFMA GEMM (hi/lo decomposition, 3 MFMAs/product),
// fused exp/crelu/alpha-pool producers that emit hi/lo bf16 + row norms,
// FC fused with L4's exp/crelu.

typedef unsigned short u16;
typedef short bf16x8 __attribute__((ext_vector_type(8)));
typedef float f32x4 __attribute__((ext_vector_type(4)));

#define STRIPES 64
#define ACC_L1 0            // 36*64*2
#define ACC_L2 4608
#define ACC_L3 4736
#define ACC_L4 4864
#define ACC_TOTAL 5120

__device__ __forceinline__ u16 f2bf(float f) {
  unsigned int u = __float_as_uint(f);
  unsigned int r = (u + 0x7fffu + ((u >> 16) & 1u)) >> 16;
  return (u16)r;
}
__device__ __forceinline__ float bf2f(u16 h) {
  return __uint_as_float(((unsigned int)h) << 16);
}
__device__ __forceinline__ void gload16(const void* g, const void* l) {
  __builtin_amdgcn_global_load_lds(
      (const __attribute__((address_space(1))) unsigned int*)g,
      (__attribute__((address_space(3))) unsigned int*)l, 16, 0, 0);
}

__global__ void zero_acc_kernel(double* __restrict__ acc) {
  int i = blockIdx.x * blockDim.x + threadIdx.x;
  if (i < ACC_TOTAL) acc[i] = 0.0;
}

// ---------------- L1 pass 1: dist + per-pos sum/sumsq (no materialization) ----------------
__global__ __launch_bounds__(128) void l1_pass1(
    const float* __restrict__ x, int c, const float* __restrict__ w1c,
    double* __restrict__ acc)
{
  __shared__ float img[784];
  __shared__ float wf[2500];
  int b = blockIdx.x, t = threadIdx.x;
  const float* xim = x + ((size_t)b * 3 + c) * 784;
  for (int i = t; i < 784; i += 128) img[i] = xim[i];
  for (int i = t; i < 2500; i += 128) wf[i] = w1c[i];
  __syncthreads();
  bool act = t < 100;
  float wreg[25];
  if (act) {
#pragma unroll
    for (int k = 0; k < 25; ++k) wreg[k] = wf[t * 25 + k];
  }
  int stripe = b & (STRIPES - 1);
  for (int pos = 0; pos < 36; ++pos) {
    int pi = pos / 6, pj = pos - pi * 6;
    double s = 0.0, qq = 0.0;
    if (act) {
      const float* p0 = &img[pi * 4 * 28 + pj * 4];
      float d2 = 0.f;
#pragma unroll
      for (int r = 0; r < 5; ++r)
#pragma unroll
        for (int s2 = 0; s2 < 5; ++s2) {
          float dd = p0[r * 28 + s2] - wreg[r * 5 + s2];
          d2 = fmaf(dd, dd, d2);
        }
      float d = sqrtf(d2 + 1e-12f);
      s = d; qq = (double)d * d;
    }
    for (int off = 32; off; off >>= 1) {
      s += __shfl_down(s, off, 64);
      qq += __shfl_down(qq, off, 64);
    }
    if ((t & 63) == 0) {
      atomicAdd(&acc[ACC_L1 + (pos * STRIPES + stripe) * 2], s);
      atomicAdd(&acc[ACC_L1 + (pos * STRIPES + stripe) * 2 + 1], qq);
    }
  }
}

__global__ void l1_fin_kernel(const double* __restrict__ acc, float* __restrict__ stds, double n) {
  int t = threadIdx.x;
  if (t < 36) {
    double s = 0.0, q = 0.0;
    for (int i = 0; i < STRIPES; ++i) {
      s += acc[ACC_L1 + (t * STRIPES + i) * 2];
      q += acc[ACC_L1 + (t * STRIPES + i) * 2 + 1];
    }
    double var = (q - s * s / n) / (n - 1.0);
    stds[t] = (float)sqrt(var > 0.0 ? var : 0.0);
  }
}

// ---------------- L1 pass 2: recompute dist -> exp/crelu -> 2x2 pool -> hi/lo + xn ----------------
__global__ __launch_bounds__(128) void l1_sfm(
    const float* __restrict__ x, int c, const float* __restrict__ w1c,
    const float* __restrict__ stds, const float* __restrict__ cb,
    u16* __restrict__ Xhi, u16* __restrict__ Xlo, float* __restrict__ xn)
{
  __shared__ float img[784];
  __shared__ float wf[2500];
  __shared__ float red[2];
  int b = blockIdx.x, t = threadIdx.x;
  const float* xim = x + ((size_t)b * 3 + c) * 784;
  for (int i = t; i < 784; i += 128) img[i] = xim[i];
  for (int i = t; i < 2500; i += 128) wf[i] = w1c[i];
  __syncthreads();
  bool act = t < 100;
  float wreg[25];
  if (act) {
#pragma unroll
    for (int k = 0; k < 25; ++k) wreg[k] = wf[t * 25 + k];
  }
  float bias = cb[0];
  const float A2[2][2] = {{0.729f, 0.81f}, {0.9f, 1.0f}};
  for (int IJ = 0; IJ < 9; ++IJ) {
    int I = IJ / 3, J = IJ - I * 3;
    float v = 0.f;
    if (act) {
      float pool = 0.f;
#pragma unroll
      for (int di = 0; di < 2; ++di)
#pragma unroll
        for (int dj = 0; dj < 2; ++dj) {
          int pi = 2 * I + di, pj = 2 * J + dj;
          const float* p0 = &img[pi * 4 * 28 + pj * 4];
          float d2 = 0.f;
#pragma unroll
          for (int r = 0; r < 5; ++r)
#pragma unroll
            for (int s2 = 0; s2 < 5; ++s2) {
              float dd = p0[r * 28 + s2] - wreg[r * 5 + s2];
              d2 = fmaf(dd, dd, d2);
            }
          float d = sqrtf(d2 + 1e-12f);
          float tt = d / stds[pi * 6 + pj];
          float e = expf(-0.5f * tt * tt);
          e = (e >= bias) ? e : 0.f;
          pool = fmaf(e, A2[di][dj], pool);
        }
      v = pool * 0.25f;
    }
    u16 h = f2bf(v);
    u16 l = f2bf(v - bf2f(h));
    size_t row = (size_t)b * 9 + IJ;
    Xhi[row * 128 + t] = h;
    Xlo[row * 128 + t] = l;
    float p = v * v;
    for (int off = 32; off; off >>= 1) p += __shfl_down(p, off, 64);
    if ((t & 63) == 0) red[t >> 6] = p;
    __syncthreads();
    if (t == 0) xn[row] = red[0] + red[1];
    __syncthreads();
  }
}

// ---------------- weight prep: fp32 -> hi/lo bf16 (padded) + row norms ----------------
__global__ __launch_bounds__(128) void w_prep(
    const float* __restrict__ W, int O, int K, int Opad, int Kp,
    u16* __restrict__ hi, u16* __restrict__ lo, float* __restrict__ wn)
{
  __shared__ float red[2];
  int o = blockIdx.x, cc = blockIdx.y, t = threadIdx.x;
  const float* src = W + ((size_t)cc * O + o) * K;
  u16* dh = hi + ((size_t)cc * Opad + o) * Kp;
  u16* dl = lo + ((size_t)cc * Opad + o) * Kp;
  float p = 0.f;
  for (int k = t; k < Kp; k += 128) {
    float v = (o < O && k < K) ? src[k] : 0.f;
    u16 h = f2bf(v);
    u16 l = f2bf(v - bf2f(h));
    dh[k] = h; dl[k] = l;
    p = fmaf(v, v, p);
  }
  for (int off = 32; off; off >>= 1) p += __shfl_down(p, off, 64);
  if ((t & 63) == 0) red[t >> 6] = p;
  __syncthreads();
  if (t == 0) wn[(size_t)cc * Opad + o] = red[0] + red[1];
}

// ---------------- split-bf16 MFMA cdist GEMM ----------------
// 128x128 tile, 4 waves, each wave 4x4 of 16x16x32 MFMA tiles, 3 MFMAs per tile (hihi,lohi,hilo).
// LDS tiles chunk-transposed: slot = q*128 + row (q = 8-elem k-chunk), 16 B/slot -> conflict-free
// ds_read_b128 frags AND contiguous global_load_lds staging.
__global__ __launch_bounds__(256) void gemm_dist_mfma(
    const u16* __restrict__ Xhi, const u16* __restrict__ Xlo,
    const u16* __restrict__ Whi, const u16* __restrict__ Wlo,
    const float* __restrict__ xn, const float* __restrict__ wn,
    float* __restrict__ dist, int O, int Kp,
    double* __restrict__ acc, int accbase)
{
  __shared__ __align__(16) u16 sm[4 * 4096];
  u16* smAh = sm;
  u16* smAl = sm + 4096;
  u16* smBh = sm + 8192;
  u16* smBl = sm + 12288;

  const int t = threadIdx.x;
  const int w = t >> 6, lane = t & 63;
  const int wr = w >> 1, wc = w & 1;
  const int m0 = blockIdx.x * 128, o0 = blockIdx.y * 128;
  const int q4 = lane >> 4, r16 = lane & 15;

  f32x4 accv[4][4];
#pragma unroll
  for (int i = 0; i < 4; ++i)
#pragma unroll
    for (int j = 0; j < 4; ++j) accv[i][j] = (f32x4){0.f, 0.f, 0.f, 0.f};

  int aoff[4], boff[4];
#pragma unroll
  for (int i = 0; i < 4; ++i) {
    aoff[i] = (q4 * 128 + wr * 64 + i * 16 + r16) * 8;
    boff[i] = (q4 * 128 + wc * 64 + i * 16 + r16) * 8;
  }

  for (int k0 = 0; k0 < Kp; k0 += 32) {
    const int kk = k0 + w * 8;   // wave w stages k-chunk q=w
#pragma unroll
    for (int u = 0; u < 2; ++u) {
      const size_t ga = (size_t)(m0 + u * 64 + lane) * Kp + kk;
      const size_t gb = (size_t)(o0 + u * 64 + lane) * Kp + kk;
      const int ls = (w * 128 + u * 64) * 8;   // uniform LDS base (+ lane*16B implicit)
      gload16(Xhi + ga, smAh + ls);
      gload16(Xlo + ga, smAl + ls);
      gload16(Whi + gb, smBh + ls);
      gload16(Wlo + gb, smBl + ls);
    }
    asm volatile("s_waitcnt vmcnt(0)" ::: "memory");
    __syncthreads();

    bf16x8 Ah[4], Al[4], Bh[4], Bl[4];
#pragma unroll
    for (int i = 0; i < 4; ++i) {
      Ah[i] = *(const bf16x8*)(smAh + aoff[i]);
      Al[i] = *(const bf16x8*)(smAl + aoff[i]);
      Bh[i] = *(const bf16x8*)(smBh + boff[i]);
      Bl[i] = *(const bf16x8*)(smBl + boff[i]);
    }
#pragma unroll
    for (int i = 0; i < 4; ++i)
#pragma unroll
      for (int j = 0; j < 4; ++j) {
        accv[i][j] = __builtin_amdgcn_mfma_f32_16x16x32_bf16(Ah[i], Bh[j], accv[i][j], 0, 0, 0);
        accv[i][j] = __builtin_amdgcn_mfma_f32_16x16x32_bf16(Al[i], Bh[j], accv[i][j], 0, 0, 0);
        accv[i][j] = __builtin_amdgcn_mfma_f32_16x16x32_bf16(Ah[i], Bl[j], accv[i][j], 0, 0, 0);
      }
    __syncthreads();
  }

  double s = 0.0, qd = 0.0;
#pragma unroll
  for (int i = 0; i < 4; ++i) {
    const int mb = m0 + wr * 64 + i * 16 + q4 * 4;   // C/D: row = quad*4 + reg
    float xnv[4];
#pragma unroll
    for (int r = 0; r < 4; ++r) xnv[r] = xn[mb + r];
#pragma unroll
    for (int j = 0; j < 4; ++j) {
      const int o = o0 + wc * 64 + j * 16 + r16;     // C/D: col = lane&15
      if (o < O) {
        const float wnv = wn[o];
#pragma unroll
        for (int r = 0; r < 4; ++r) {
          float d2 = xnv[r] + wnv - 2.f * accv[i][j][r];
          float d = sqrtf(fmaxf(d2, 0.f) + 1e-12f);
          dist[(size_t)(mb + r) * O + o] = d;
          s += d; qd += (double)d * d;
        }
      }
    }
  }
  for (int off = 32; off; off >>= 1) {
    s += __shfl_down(s, off, 64);
    qd += __shfl_down(qd, off, 64);
  }
  if (lane == 0) {
    int stripe = (blockIdx.x + blockIdx.y * gridDim.x) & (STRIPES - 1);
    atomicAdd(&acc[accbase + stripe * 2], s);
    atomicAdd(&acc[accbase + stripe * 2 + 1], qd);
  }
}

__global__ void gen_fin_kernel(const double* __restrict__ acc, int base, double n,
                               float* __restrict__ stds, int slot)
{
  int t = threadIdx.x;  // 64
  double s = acc[base + t * 2], q = acc[base + t * 2 + 1];
  for (int off = 32; off; off >>= 1) {
    s += __shfl_down(s, off, 64);
    q += __shfl_down(q, off, 64);
  }
  if (t == 0) {
    double var = (q - s * s / n) / (n - 1.0);
    stds[slot] = (float)sqrt(var > 0.0 ? var : 0.0);
  }
}

// exp -> crelu(cb1) -> [0.81,0.9,1]/3 pool -> hi/lo (Kp=256) + xn
__global__ __launch_bounds__(256) void l2_sfm(
    const float* __restrict__ dist2, const float* __restrict__ stds,
    const float* __restrict__ cb, u16* __restrict__ Xhi, u16* __restrict__ Xlo,
    float* __restrict__ xn)
{
  __shared__ float red[4];
  int b = blockIdx.x, u = blockIdx.y, ch = threadIdx.x;
  float sd = stds[36], bias = cb[1];
  float v = 0.f;
  if (ch < 225) {
    const float av[3] = {0.81f, 0.9f, 1.0f};
    float a = 0.f;
#pragma unroll
    for (int vv = 0; vv < 3; ++vv) {
      float d = dist2[((size_t)b * 9 + u * 3 + vv) * 225 + ch];
      float tt = d / sd;
      float e = expf(-0.5f * tt * tt);
      e = (e >= bias) ? e : 0.f;
      a = fmaf(e, av[vv], a);
    }
    v = a * (1.f / 3.f);
  }
  size_t row = (size_t)b * 3 + u;
  u16 h = f2bf(v);
  u16 l = f2bf(v - bf2f(h));
  Xhi[row * 256 + ch] = h;
  Xlo[row * 256 + ch] = l;
  float p = v * v;
  for (int off = 32; off; off >>= 1) p += __shfl_down(p, off, 64);
  if ((ch & 63) == 0) red[ch >> 6] = p;
  __syncthreads();
  if (ch == 0) xn[row] = red[0] + red[1] + red[2] + red[3];
}

// exp -> crelu(cb2) -> [0.81,0.9,1]/3 pool -> hi/lo (Kp=640) + xn
__global__ __launch_bounds__(256) void l3_sfm(
    const float* __restrict__ dist3, const float* __restrict__ stds,
    const float* __restrict__ cb, u16* __restrict__ Xhi, u16* __restrict__ Xlo,
    float* __restrict__ xn)
{
  __shared__ float red[4];
  int b = blockIdx.x, t = threadIdx.x;
  float sd = stds[37], bias = cb[2];
  const float au[3] = {0.81f, 0.9f, 1.0f};
  float p = 0.f;
  for (int ch = t; ch < 640; ch += 256) {
    float v = 0.f;
    if (ch < 625) {
      float a = 0.f;
#pragma unroll
      for (int u = 0; u < 3; ++u) {
        float d = dist3[((size_t)b * 3 + u) * 625 + ch];
        float tt = d / sd;
        float e = expf(-0.5f * tt * tt);
        e = (e >= bias) ? e : 0.f;
        a = fmaf(e, au[u], a);
      }
      v = a * (1.f / 3.f);
    }
    u16 h = f2bf(v);
    u16 l = f2bf(v - bf2f(h));
    Xhi[(size_t)b * 640 + ch] = h;
    Xlo[(size_t)b * 640 + ch] = l;
    p = fmaf(v, v, p);
  }
  for (int off = 32; off; off >>= 1) p += __shfl_down(p, off, 64);
  if ((t & 63) == 0) red[t >> 6] = p;
  __syncthreads();
  if (t == 0) xn[b] = red[0] + red[1] + red[2] + red[3];
}

// L4 exp/crelu fused into FC: out[b,:] (+)= act(dist4[b,:]) @ fcw_c^T (+fcb on c==0)
__global__ __launch_bounds__(128) void fc_acc(
    const float* __restrict__ dist4, const float* __restrict__ stds,
    const float* __restrict__ cb, const float* __restrict__ fcw,
    const float* __restrict__ fcb, float* __restrict__ out, int c)
{
  int b = blockIdx.x, t = threadIdx.x;
  float sd = stds[38], bias = cb[3];
  float p[10];
#pragma unroll
  for (int k = 0; k < 10; ++k) p[k] = 0.f;
  for (int j = t; j < 1225; j += 128) {
    float d = dist4[(size_t)b * 1225 + j];
    float tt = d / sd;
    float v = expf(-0.5f * tt * tt);
    v = (v >= bias) ? v : 0.f;
#pragma unroll
    for (int k = 0; k < 10; ++k) p[k] = fmaf(v, fcw[k * 3675 + c * 1225 + j], p[k]);
  }
#pragma unroll
  for (int k = 0; k < 10; ++k)
    for (int off = 32; off; off >>= 1) p[k] += __shfl_down(p[k], off, 64);
  __shared__ float red[2][10];
  int wave = t >> 6;
  if ((t & 63) == 0) {
#pragma unroll
    for (int k = 0; k < 10; ++k) red[wave][k] = p[k];
  }
  __syncthreads();
  if (t < 10) {
    float v = red[0][t] + red[1][t];
    if (c == 0) out[(size_t)b * 10 + t] = fcb[t] + v;
    else        out[(size_t)b * 10 + t] += v;
  }
}

extern "C" void kernel_launch(void* const* d_in, const int* in_sizes, int n_in,
                              void* d_out, int out_size, void* d_ws, size_t ws_size,
                              hipStream_t stream) {
  const float* x   = (const float*)d_in[0];
  const float* w1  = (const float*)d_in[1];
  const float* w2  = (const float*)d_in[2];
  const float* w3  = (const float*)d_in[3];
  const float* w4  = (const float*)d_in[4];
  const float* fcw = (const float*)d_in[5];
  const float* fcb = (const float*)d_in[6];
  const float* cb  = (const float*)d_in[7];
  float* out = (float*)d_out;
  int B = in_sizes[0] / (3 * 28 * 28);   // 4096 (multiple of 128 assumed via B*9, B*3, B)
  int M2 = B * 9, M3 = B * 3;

  // workspace layout
  float* distA = (float*)d_ws;                        // 8,294,400 fl (36864*225 max)
  float* xn    = distA + 8294400;                     // 36,864 fl
  float* stds  = xn + 36864;                          // 64 fl
  double* accd = (double*)(stds + 64);                // 5120 dbl
  u16* Xhi = (u16*)(accd + ACC_TOTAL);                // 4,718,592 u16 (36864*128)
  u16* Xlo = Xhi + 4718592;
  u16* Whi = Xlo + 4718592;                           // 3,047,424 u16
  u16* Wlo = Whi + 3047424;
  float* wn = (float*)(Wlo + 3047424);                // 6,528 fl
  u16* Whi2 = Whi;            u16* Wlo2 = Wlo;            float* wn2 = wn;
  u16* Whi3 = Whi + 98304;    u16* Wlo3 = Wlo + 98304;    float* wn3 = wn + 768;
  u16* Whi4 = Whi + 589824;   u16* Wlo4 = Wlo + 589824;   float* wn4 = wn + 2688;

  // weight prep (all channels)
  w_prep<<<dim3(256, 3),  128, 0, stream>>>(w2, 225, 100, 256, 128, Whi2, Wlo2, wn2);
  w_prep<<<dim3(640, 3),  128, 0, stream>>>(w3, 625, 225, 640, 256, Whi3, Wlo3, wn3);
  w_prep<<<dim3(1280, 3), 128, 0, stream>>>(w4, 1225, 625, 1280, 640, Whi4, Wlo4, wn4);

  for (int c = 0; c < 3; ++c) {
    const float* w1c = w1 + (size_t)c * 2500;

    zero_acc_kernel<<<(ACC_TOTAL + 255) / 256, 256, 0, stream>>>(accd);

    // L1
    l1_pass1<<<B, 128, 0, stream>>>(x, c, w1c, accd);
    l1_fin_kernel<<<1, 64, 0, stream>>>(accd, stds, (double)B * 100.0);
    l1_sfm<<<B, 128, 0, stream>>>(x, c, w1c, stds, cb, Xhi, Xlo, xn);

    // L2: (M2 x 128) x (256 x 128) -> dist2 (M2 x 225)
    gemm_dist_mfma<<<dim3(M2 / 128, 2), 256, 0, stream>>>(
        Xhi, Xlo, Whi2 + (size_t)c * 256 * 128, Wlo2 + (size_t)c * 256 * 128,
        xn, wn2 + c * 256, distA, 225, 128, accd, ACC_L2);
    gen_fin_kernel<<<1, 64, 0, stream>>>(accd, ACC_L2, (double)M2 * 225.0, stds, 36);
    l2_sfm<<<dim3(B, 3), 256, 0, stream>>>(distA, stds, cb, Xhi, Xlo, xn);

    // L3: (M3 x 256) x (640 x 256) -> dist3 (M3 x 625)
    gemm_dist_mfma<<<dim3(M3 / 128, 5), 256, 0, stream>>>(
        Xhi, Xlo, Whi3 + (size_t)c * 640 * 256, Wlo3 + (size_t)c * 640 * 256,
        xn, wn3 + c * 640, distA, 625, 256, accd, ACC_L3);
    gen_fin_kernel<<<1, 64, 0, stream>>>(accd, ACC_L3, (double)M3 * 625.0, stds, 37);
    l3_sfm<<<B, 256, 0, stream>>>(distA, stds, cb, Xhi, Xlo, xn);

    // L4: (B x 640) x (1280 x 640) -> dist4 (B x 1225)
    gemm_dist_mfma<<<dim3(B / 128, 10), 256, 0, stream>>>(
        Xhi, Xlo, Whi4 + (size_t)c * 1280 * 640, Wlo4 + (size_t)c * 1280 * 640,
        xn, wn4 + c * 1280, distA, 1225, 640, accd, ACC_L4);
    gen_fin_kernel<<<1, 64, 0, stream>>>(accd, ACC_L4, (double)B * 1225.0, stds, 38);

    fc_acc<<<B, 128, 0, stream>>>(distA, stds, cb, fcw, fcb, out, c);
  }
}

// Round 3
// 962.009 us; speedup vs baseline: 1.4963x; 1.0949x over previous
//
#include <hip/hip_runtime.h>

// SOMNetwork forward. All four rbf/cdist layers via split-bf16 MFMA GEMM
// (hi/lo decomposition, 3 MFMAs/product). L1 uses a padded patch matrix
// (64 rows/image, K=32) with a two-pass GEMM: pass A fused std-reduce,
// pass B fused exp/crelu/2x2-alpha-pool epilogue (no dist1 materialization).
// L2/L3/L4 std-finalize folded into consumer kernel preambles.

typedef unsigned short u16;
typedef short bf16x8 __attribute__((ext_vector_type(8)));
typedef float f32x4 __attribute__((ext_vector_type(4)));

#define STRIPES 64
#define ACC_L1 0            // 36*64*2
#define ACC_L2 4608
#define ACC_L3 4736
#define ACC_L4 4864
#define ACC_TOTAL 5120
#define ESM_P 132           // padded e_sm row (bank-conflict relief)

__device__ __forceinline__ u16 f2bf(float f) {
  unsigned int u = __float_as_uint(f);
  unsigned int r = (u + 0x7fffu + ((u >> 16) & 1u)) >> 16;
  return (u16)r;
}
__device__ __forceinline__ float bf2f(u16 h) {
  return __uint_as_float(((unsigned int)h) << 16);
}
__device__ __forceinline__ void gload16(const void* g, const void* l) {
  __builtin_amdgcn_global_load_lds(
      (const __attribute__((address_space(1))) unsigned int*)g,
      (__attribute__((address_space(3))) unsigned int*)l, 16, 0, 0);
}

__global__ void zero_acc_kernel(double* __restrict__ acc, int n) {
  int i = blockIdx.x * blockDim.x + threadIdx.x;
  if (i < n) acc[i] = 0.0;
}

// ---------------- weight prep: fp32 -> hi/lo bf16 (padded) + row norms ----------------
__global__ __launch_bounds__(128) void w_prep(
    const float* __restrict__ W, int O, int K, int Opad, int Kp,
    u16* __restrict__ hi, u16* __restrict__ lo, float* __restrict__ wn)
{
  __shared__ float red[2];
  int o = blockIdx.x, cc = blockIdx.y, t = threadIdx.x;
  const float* src = W + ((size_t)cc * O + o) * K;
  u16* dh = hi + ((size_t)cc * Opad + o) * Kp;
  u16* dl = lo + ((size_t)cc * Opad + o) * Kp;
  float p = 0.f;
  for (int k = t; k < Kp; k += 128) {
    float v = (o < O && k < K) ? src[k] : 0.f;
    u16 h = f2bf(v);
    u16 l = f2bf(v - bf2f(h));
    dh[k] = h; dl[k] = l;
    p = fmaf(v, v, p);
  }
  for (int off = 32; off; off >>= 1) p += __shfl_down(p, off, 64);
  if ((t & 63) == 0) red[t >> 6] = p;
  __syncthreads();
  if (t == 0) wn[(size_t)cc * Opad + o] = red[0] + red[1];
}

// ---------------- L1 patch extraction: (B images) -> P (B*64 x 32) hi/lo + pnorm ----------------
__global__ __launch_bounds__(128) void l1_extract(
    const float* __restrict__ x, int c,
    u16* __restrict__ Ph, u16* __restrict__ Pl, float* __restrict__ pnorm)
{
  __shared__ float img[784];
  int b = blockIdx.x, t = threadIdx.x;
  const float4* xim = (const float4*)(x + ((size_t)b * 3 + c) * 784);
  ((float4*)img)[t] = xim[t];
  if (t < 68) ((float4*)img)[128 + t] = xim[128 + t];
  __syncthreads();
  size_t base = (size_t)b * 64;
  int kk = t & 31, sub = t >> 5;
#pragma unroll
  for (int it = 0; it < 16; ++it) {
    int row = it * 4 + sub;
    float val = 0.f;
    if (row < 36 && kk < 25) {
      int pi = row / 6, pj = row - pi * 6;
      int r = kk / 5, s = kk - r * 5;
      val = img[(pi * 4 + r) * 28 + pj * 4 + s];
    }
    u16 h = f2bf(val);
    u16 l = f2bf(val - bf2f(h));
    Ph[(base + row) * 32 + kk] = h;
    Pl[(base + row) * 32 + kk] = l;
    float p = val * val;
    p += __shfl_down(p, 16, 32);
    p += __shfl_down(p, 8, 32);
    p += __shfl_down(p, 4, 32);
    p += __shfl_down(p, 2, 32);
    p += __shfl_down(p, 1, 32);
    if (kk == 0) pnorm[base + row] = p;
  }
}

// ---------------- shared L1 GEMM mainloop (M tile 128, O=128, K=32, 1 staging step) ----------------
#define L1_MAINLOOP(Ph, Pl, Wh, Wl, m0, sm, accv)                              \
  {                                                                            \
    u16* smAh = sm; u16* smAl = sm + 4096;                                     \
    u16* smBh = sm + 8192; u16* smBl = sm + 12288;                             \
    const int t_ = threadIdx.x;                                                \
    const int w_ = t_ >> 6, lane_ = t_ & 63;                                   \
    const int kk_ = w_ * 8;                                                    \
    _Pragma("unroll")                                                          \
    for (int u = 0; u < 2; ++u) {                                              \
      const size_t ga = (size_t)(m0 + u * 64 + lane_) * 32 + kk_;              \
      const size_t gb = (size_t)(u * 64 + lane_) * 32 + kk_;                   \
      const int ls = (w_ * 128 + u * 64) * 8;                                  \
      gload16(Ph + ga, smAh + ls); gload16(Pl + ga, smAl + ls);                \
      gload16(Wh + gb, smBh + ls); gload16(Wl + gb, smBl + ls);                \
    }                                                                          \
    asm volatile("s_waitcnt vmcnt(0)" ::: "memory");                           \
    __syncthreads();                                                           \
    const int wr_ = w_ >> 1, wc_ = w_ & 1;                                     \
    const int q4_ = lane_ >> 4, r16_ = lane_ & 15;                             \
    bf16x8 Ah[4], Al[4], Bh[4], Bl[4];                                         \
    _Pragma("unroll")                                                          \
    for (int i = 0; i < 4; ++i) {                                              \
      int ao = (q4_ * 128 + wr_ * 64 + i * 16 + r16_) * 8;                     \
      int bo = (q4_ * 128 + wc_ * 64 + i * 16 + r16_) * 8;                     \
      Ah[i] = *(const bf16x8*)(smAh + ao);                                     \
      Al[i] = *(const bf16x8*)(smAl + ao);                                     \
      Bh[i] = *(const bf16x8*)(smBh + bo);                                     \
      Bl[i] = *(const bf16x8*)(smBl + bo);                                     \
    }                                                                          \
    _Pragma("unroll")                                                          \
    for (int i = 0; i < 4; ++i)                                                \
      _Pragma("unroll")                                                        \
      for (int j = 0; j < 4; ++j) {                                            \
        accv[i][j] = __builtin_amdgcn_mfma_f32_16x16x32_bf16(Ah[i], Bh[j], accv[i][j], 0, 0, 0); \
        accv[i][j] = __builtin_amdgcn_mfma_f32_16x16x32_bf16(Al[i], Bh[j], accv[i][j], 0, 0, 0); \
        accv[i][j] = __builtin_amdgcn_mfma_f32_16x16x32_bf16(Ah[i], Bl[j], accv[i][j], 0, 0, 0); \
      }                                                                        \
  }

// ---------------- L1 GEMM pass A: per-position s/q reduce only ----------------
__global__ __launch_bounds__(256) void l1_gemm_reduce(
    const u16* __restrict__ Ph, const u16* __restrict__ Pl,
    const u16* __restrict__ Wh, const u16* __restrict__ Wl,
    const float* __restrict__ pnorm, const float* __restrict__ wn,
    double* __restrict__ acc)
{
  __shared__ __align__(16) u16 sm[16384];
  f32x4 accv[4][4];
#pragma unroll
  for (int i = 0; i < 4; ++i)
#pragma unroll
    for (int j = 0; j < 4; ++j) accv[i][j] = (f32x4){0.f, 0.f, 0.f, 0.f};
  const int m0 = blockIdx.x * 128;
  L1_MAINLOOP(Ph, Pl, Wh, Wl, m0, sm, accv);

  const int t = threadIdx.x, w = t >> 6, lane = t & 63;
  const int wr = w >> 1, wc = w & 1, q4 = lane >> 4, r16 = lane & 15;
  const int stripe = blockIdx.x & (STRIPES - 1);
#pragma unroll
  for (int i = 0; i < 4; ++i) {
#pragma unroll
    for (int r = 0; r < 4; ++r) {
      int pos = i * 16 + q4 * 4 + r;
      if (pos < 36) {
        float pn = pnorm[m0 + wr * 64 + pos];
        float s = 0.f, q = 0.f;
#pragma unroll
        for (int j = 0; j < 4; ++j) {
          int col = wc * 64 + j * 16 + r16;
          if (col < 100) {
            float d2 = pn + wn[col] - 2.f * accv[i][j][r];
            float d2c = fmaxf(d2, 0.f) + 1e-12f;
            s += sqrtf(d2c);
            q += d2c;
          }
        }
        s += __shfl_down(s, 8, 16);
        s += __shfl_down(s, 4, 16);
        s += __shfl_down(s, 2, 16);
        s += __shfl_down(s, 1, 16);
        q += __shfl_down(q, 8, 16);
        q += __shfl_down(q, 4, 16);
        q += __shfl_down(q, 2, 16);
        q += __shfl_down(q, 1, 16);
        if (r16 == 0) {
          atomicAdd(&acc[ACC_L1 + (pos * STRIPES + stripe) * 2], (double)s);
          atomicAdd(&acc[ACC_L1 + (pos * STRIPES + stripe) * 2 + 1], (double)q);
        }
      }
    }
  }
}

__global__ void l1_fin(const double* __restrict__ acc, float* __restrict__ inv36, double n) {
  int t = threadIdx.x;
  if (t < 36) {
    double s = 0.0, q = 0.0;
    for (int i = 0; i < STRIPES; ++i) {
      s += acc[ACC_L1 + (t * STRIPES + i) * 2];
      q += acc[ACC_L1 + (t * STRIPES + i) * 2 + 1];
    }
    double var = (q - s * s / n) / (n - 1.0);
    inv36[t] = var > 0.0 ? (float)(0.5 / var) : __builtin_inff();
  }
}

// ---------------- L1 GEMM pass B: fused exp/crelu/2x2-alpha-pool epilogue ----------------
__global__ __launch_bounds__(256) void l1_gemm_sfm(
    const u16* __restrict__ Ph, const u16* __restrict__ Pl,
    const u16* __restrict__ Wh, const u16* __restrict__ Wl,
    const float* __restrict__ pnorm, const float* __restrict__ wn,
    const float* __restrict__ inv36, const float* __restrict__ cb,
    u16* __restrict__ Xhi, u16* __restrict__ Xlo, float* __restrict__ xn)
{
  __shared__ __align__(16) u16 sm[16384];
  __shared__ float esm[2 * 36 * ESM_P];
  __shared__ float inv_s[36];
  __shared__ float xnsm[18];
  int t = threadIdx.x;
  if (t < 36) inv_s[t] = inv36[t];
  if (t < 18) xnsm[t] = 0.f;
  f32x4 accv[4][4];
#pragma unroll
  for (int i = 0; i < 4; ++i)
#pragma unroll
    for (int j = 0; j < 4; ++j) accv[i][j] = (f32x4){0.f, 0.f, 0.f, 0.f};
  const int m0 = blockIdx.x * 128;
  L1_MAINLOOP(Ph, Pl, Wh, Wl, m0, sm, accv);

  const float bias = cb[0];
  const int w = t >> 6, lane = t & 63;
  const int wr = w >> 1, wc = w & 1, q4 = lane >> 4, r16 = lane & 15;
#pragma unroll
  for (int i = 0; i < 4; ++i) {
#pragma unroll
    for (int r = 0; r < 4; ++r) {
      int pos = i * 16 + q4 * 4 + r;
      if (pos < 36) {
        float pn = pnorm[m0 + wr * 64 + pos];
        float inv = inv_s[pos];
#pragma unroll
        for (int j = 0; j < 4; ++j) {
          int col = wc * 64 + j * 16 + r16;
          float d2 = pn + wn[col] - 2.f * accv[i][j][r];
          float d2c = fmaxf(d2, 0.f) + 1e-12f;
          float e = expf(-d2c * inv);
          e = (e >= bias) ? e : 0.f;
          esm[(wr * 36 + pos) * ESM_P + col] = e;
        }
      }
    }
  }
  __syncthreads();

  size_t b0 = (size_t)blockIdx.x * 2;   // first image of the pair
#pragma unroll
  for (int it = 0; it < 9; ++it) {
    int idx = t + 256 * it;
    int rowp = idx >> 7;       // 0..17 = im*9 + IJ
    int col = idx & 127;
    int im = rowp / 9, IJ = rowp - im * 9;
    int I = IJ / 3, J = IJ - I * 3;
    int p00 = 12 * I + 2 * J;
    const float* eb = &esm[im * 36 * ESM_P + col];
    float v = 0.f;
    if (col < 100) {
      v = 0.729f * eb[p00 * ESM_P] + 0.81f * eb[(p00 + 1) * ESM_P] +
          0.9f * eb[(p00 + 6) * ESM_P] + eb[(p00 + 7) * ESM_P];
      v *= 0.25f;
    }
    u16 h = f2bf(v);
    u16 l = f2bf(v - bf2f(h));
    size_t xrow = b0 * 9 + rowp;
    Xhi[xrow * 128 + col] = h;
    Xlo[xrow * 128 + col] = l;
    float p = v * v;
    for (int off = 32; off; off >>= 1) p += __shfl_down(p, off, 64);
    if ((t & 63) == 0) atomicAdd(&xnsm[rowp], p);
  }
  __syncthreads();
  if (t < 18) xn[b0 * 9 + t] = xnsm[t];
}

// ---------------- split-bf16 MFMA cdist GEMM (L2/L3/L4), fused s/q reduce ----------------
__global__ __launch_bounds__(256) void gemm_dist_mfma(
    const u16* __restrict__ Xhi, const u16* __restrict__ Xlo,
    const u16* __restrict__ Whi, const u16* __restrict__ Wlo,
    const float* __restrict__ xn, const float* __restrict__ wn,
    float* __restrict__ dist, int O, int Kp,
    double* __restrict__ acc, int accbase)
{
  __shared__ __align__(16) u16 sm[4 * 4096];
  u16* smAh = sm;
  u16* smAl = sm + 4096;
  u16* smBh = sm + 8192;
  u16* smBl = sm + 12288;

  const int t = threadIdx.x;
  const int w = t >> 6, lane = t & 63;
  const int wr = w >> 1, wc = w & 1;
  const int m0 = blockIdx.x * 128, o0 = blockIdx.y * 128;
  const int q4 = lane >> 4, r16 = lane & 15;

  f32x4 accv[4][4];
#pragma unroll
  for (int i = 0; i < 4; ++i)
#pragma unroll
    for (int j = 0; j < 4; ++j) accv[i][j] = (f32x4){0.f, 0.f, 0.f, 0.f};

  int aoff[4], boff[4];
#pragma unroll
  for (int i = 0; i < 4; ++i) {
    aoff[i] = (q4 * 128 + wr * 64 + i * 16 + r16) * 8;
    boff[i] = (q4 * 128 + wc * 64 + i * 16 + r16) * 8;
  }

  for (int k0 = 0; k0 < Kp; k0 += 32) {
    const int kk = k0 + w * 8;
#pragma unroll
    for (int u = 0; u < 2; ++u) {
      const size_t ga = (size_t)(m0 + u * 64 + lane) * Kp + kk;
      const size_t gb = (size_t)(o0 + u * 64 + lane) * Kp + kk;
      const int ls = (w * 128 + u * 64) * 8;
      gload16(Xhi + ga, smAh + ls);
      gload16(Xlo + ga, smAl + ls);
      gload16(Whi + gb, smBh + ls);
      gload16(Wlo + gb, smBl + ls);
    }
    asm volatile("s_waitcnt vmcnt(0)" ::: "memory");
    __syncthreads();

    bf16x8 Ah[4], Al[4], Bh[4], Bl[4];
#pragma unroll
    for (int i = 0; i < 4; ++i) {
      Ah[i] = *(const bf16x8*)(smAh + aoff[i]);
      Al[i] = *(const bf16x8*)(smAl + aoff[i]);
      Bh[i] = *(const bf16x8*)(smBh + boff[i]);
      Bl[i] = *(const bf16x8*)(smBl + boff[i]);
    }
#pragma unroll
    for (int i = 0; i < 4; ++i)
#pragma unroll
      for (int j = 0; j < 4; ++j) {
        accv[i][j] = __builtin_amdgcn_mfma_f32_16x16x32_bf16(Ah[i], Bh[j], accv[i][j], 0, 0, 0);
        accv[i][j] = __builtin_amdgcn_mfma_f32_16x16x32_bf16(Al[i], Bh[j], accv[i][j], 0, 0, 0);
        accv[i][j] = __builtin_amdgcn_mfma_f32_16x16x32_bf16(Ah[i], Bl[j], accv[i][j], 0, 0, 0);
      }
    __syncthreads();
  }

  double s = 0.0, qd = 0.0;
#pragma unroll
  for (int i = 0; i < 4; ++i) {
    const int mb = m0 + wr * 64 + i * 16 + q4 * 4;
    float xnv[4];
#pragma unroll
    for (int r = 0; r < 4; ++r) xnv[r] = xn[mb + r];
#pragma unroll
    for (int j = 0; j < 4; ++j) {
      const int o = o0 + wc * 64 + j * 16 + r16;
      if (o < O) {
        const float wnv = wn[o];
#pragma unroll
        for (int r = 0; r < 4; ++r) {
          float d2 = xnv[r] + wnv - 2.f * accv[i][j][r];
          float d = sqrtf(fmaxf(d2, 0.f) + 1e-12f);
          dist[(size_t)(mb + r) * O + o] = d;
          s += d; qd += (double)d * d;
        }
      }
    }
  }
  for (int off = 32; off; off >>= 1) {
    s += __shfl_down(s, off, 64);
    qd += __shfl_down(qd, off, 64);
  }
  if (lane == 0) {
    int stripe = (blockIdx.x + blockIdx.y * gridDim.x) & (STRIPES - 1);
    atomicAdd(&acc[accbase + stripe * 2], s);
    atomicAdd(&acc[accbase + stripe * 2 + 1], qd);
  }
}

// block preamble: reduce 64-stripe acc -> inv = 0.5/var, broadcast via LDS
__device__ __forceinline__ float block_inv_from_acc(
    const double* __restrict__ acc, int base, double n, float* sh)
{
  int t = threadIdx.x;
  if (t < 64) {
    double s = acc[base + 2 * t], q = acc[base + 2 * t + 1];
    for (int off = 32; off; off >>= 1) {
      s += __shfl_down(s, off, 64);
      q += __shfl_down(q, off, 64);
    }
    if (t == 0) {
      double var = (q - s * s / n) / (n - 1.0);
      *sh = var > 0.0 ? (float)(0.5 / var) : __builtin_inff();
    }
  }
  __syncthreads();
  return *sh;
}

// exp -> crelu(cb1) -> [0.81,0.9,1]/3 pool -> hi/lo (Kp=256) + xn
__global__ __launch_bounds__(256) void l2_sfm(
    const float* __restrict__ dist2, const double* __restrict__ acc, double n,
    const float* __restrict__ cb, u16* __restrict__ Xhi, u16* __restrict__ Xlo,
    float* __restrict__ xn)
{
  __shared__ float shinv;
  __shared__ float red[4];
  float inv = block_inv_from_acc(acc, ACC_L2, n, &shinv);
  int b = blockIdx.x, u = blockIdx.y, ch = threadIdx.x;
  float bias = cb[1];
  float v = 0.f;
  if (ch < 225) {
    const float av[3] = {0.81f, 0.9f, 1.0f};
    float a = 0.f;
#pragma unroll
    for (int vv = 0; vv < 3; ++vv) {
      float d = dist2[((size_t)b * 9 + u * 3 + vv) * 225 + ch];
      float e = expf(-d * d * inv);
      e = (e >= bias) ? e : 0.f;
      a = fmaf(e, av[vv], a);
    }
    v = a * (1.f / 3.f);
  }
  size_t row = (size_t)b * 3 + u;
  u16 h = f2bf(v);
  u16 l = f2bf(v - bf2f(h));
  Xhi[row * 256 + ch] = h;
  Xlo[row * 256 + ch] = l;
  float p = v * v;
  for (int off = 32; off; off >>= 1) p += __shfl_down(p, off, 64);
  if ((ch & 63) == 0) red[ch >> 6] = p;
  __syncthreads();
  if (ch == 0) xn[row] = red[0] + red[1] + red[2] + red[3];
}

// exp -> crelu(cb2) -> [0.81,0.9,1]/3 pool -> hi/lo (Kp=640) + xn
__global__ __launch_bounds__(256) void l3_sfm(
    const float* __restrict__ dist3, const double* __restrict__ acc, double n,
    const float* __restrict__ cb, u16* __restrict__ Xhi, u16* __restrict__ Xlo,
    float* __restrict__ xn)
{
  __shared__ float shinv;
  __shared__ float red[4];
  float inv = block_inv_from_acc(acc, ACC_L3, n, &shinv);
  int b = blockIdx.x, t = threadIdx.x;
  float bias = cb[2];
  const float au[3] = {0.81f, 0.9f, 1.0f};
  float p = 0.f;
  for (int ch = t; ch < 640; ch += 256) {
    float v = 0.f;
    if (ch < 625) {
      float a = 0.f;
#pragma unroll
      for (int u = 0; u < 3; ++u) {
        float d = dist3[((size_t)b * 3 + u) * 625 + ch];
        float e = expf(-d * d * inv);
        e = (e >= bias) ? e : 0.f;
        a = fmaf(e, au[u], a);
      }
      v = a * (1.f / 3.f);
    }
    u16 h = f2bf(v);
    u16 l = f2bf(v - bf2f(h));
    Xhi[(size_t)b * 640 + ch] = h;
    Xlo[(size_t)b * 640 + ch] = l;
    p = fmaf(v, v, p);
  }
  for (int off = 32; off; off >>= 1) p += __shfl_down(p, off, 64);
  if ((t & 63) == 0) red[t >> 6] = p;
  __syncthreads();
  if (t == 0) xn[b] = red[0] + red[1] + red[2] + red[3];
}

// L4 exp/crelu fused into FC: out[b,:] (+)= act(dist4[b,:]) @ fcw_c^T (+fcb on c==0)
__global__ __launch_bounds__(128) void fc_acc(
    const float* __restrict__ dist4, const double* __restrict__ acc, double n,
    const float* __restrict__ cb, const float* __restrict__ fcw,
    const float* __restrict__ fcb, float* __restrict__ out, int c)
{
  __shared__ float shinv;
  float inv = block_inv_from_acc(acc, ACC_L4, n, &shinv);
  int b = blockIdx.x, t = threadIdx.x;
  float bias = cb[3];
  float p[10];
#pragma unroll
  for (int k = 0; k < 10; ++k) p[k] = 0.f;
  for (int j = t; j < 1225; j += 128) {
    float d = dist4[(size_t)b * 1225 + j];
    float v = expf(-d * d * inv);
    v = (v >= bias) ? v : 0.f;
#pragma unroll
    for (int k = 0; k < 10; ++k) p[k] = fmaf(v, fcw[k * 3675 + c * 1225 + j], p[k]);
  }
#pragma unroll
  for (int k = 0; k < 10; ++k)
    for (int off = 32; off; off >>= 1) p[k] += __shfl_down(p[k], off, 64);
  __shared__ float red[2][10];
  int wave = t >> 6;
  if ((t & 63) == 0) {
#pragma unroll
    for (int k = 0; k < 10; ++k) red[wave][k] = p[k];
  }
  __syncthreads();
  if (t < 10) {
    float v = red[0][t] + red[1][t];
    if (c == 0) out[(size_t)b * 10 + t] = fcb[t] + v;
    else        out[(size_t)b * 10 + t] += v;
  }
}

extern "C" void kernel_launch(void* const* d_in, const int* in_sizes, int n_in,
                              void* d_out, int out_size, void* d_ws, size_t ws_size,
                              hipStream_t stream) {
  const float* x   = (const float*)d_in[0];
  const float* w1  = (const float*)d_in[1];
  const float* w2  = (const float*)d_in[2];
  const float* w3  = (const float*)d_in[3];
  const float* w4  = (const float*)d_in[4];
  const float* fcw = (const float*)d_in[5];
  const float* fcb = (const float*)d_in[6];
  const float* cb  = (const float*)d_in[7];
  float* out = (float*)d_out;
  int B = in_sizes[0] / (3 * 28 * 28);   // 4096
  int M2 = B * 9, M3 = B * 3;

  // workspace layout (bytes)
  char* p = (char*)d_ws;
  u16* Ph = (u16*)p;                         // B*64*32 u16 = 16.78 MB
  u16* Pl = Ph + (size_t)B * 64 * 32;        // region1 total 33.55 MB,
  float* distA = (float*)Ph;                 //   aliased with dist2/3/4 (<=33.2 MB)
  char* q = p + (size_t)B * 64 * 32 * 2 * 2;
  u16* Xhi = (u16*)q;                        // 36864*128 u16 = 9.44 MB
  u16* Xlo = Xhi + (size_t)M2 * 128;
  u16* Whi = Xlo + (size_t)M2 * 128;         // 3*(256*128+640*256+1280*640) u16
  u16* Wlo = Whi + 3047424;
  u16* W1h = Wlo + 3047424;                  // 3*128*32
  u16* W1l = W1h + 12288;
  float* wn  = (float*)(W1l + 12288);        // 6528
  float* w1n = wn + 6528;                    // 384
  float* pnorm = w1n + 384;                  // B*64
  float* xn = pnorm + (size_t)B * 64;        // M2
  float* inv36 = xn + M2;                    // 64
  double* accd = (double*)(inv36 + 64);      // 3*ACC_TOTAL
  u16* Whi2 = Whi;            u16* Wlo2 = Wlo;            float* wn2 = wn;
  u16* Whi3 = Whi + 98304;    u16* Wlo3 = Wlo + 98304;    float* wn3 = wn + 768;
  u16* Whi4 = Whi + 589824;   u16* Wlo4 = Wlo + 589824;   float* wn4 = wn + 2688;

  // upfront: zero all acc, prep all weights
  zero_acc_kernel<<<(3 * ACC_TOTAL + 255) / 256, 256, 0, stream>>>(accd, 3 * ACC_TOTAL);
  w_prep<<<dim3(128, 3),  128, 0, stream>>>(w1, 100, 25,  128, 32,  W1h,  W1l,  w1n);
  w_prep<<<dim3(256, 3),  128, 0, stream>>>(w2, 225, 100, 256, 128, Whi2, Wlo2, wn2);
  w_prep<<<dim3(640, 3),  128, 0, stream>>>(w3, 625, 225, 640, 256, Whi3, Wlo3, wn3);
  w_prep<<<dim3(1280, 3), 128, 0, stream>>>(w4, 1225, 625, 1280, 640, Whi4, Wlo4, wn4);

  for (int c = 0; c < 3; ++c) {
    double* accC = accd + (size_t)c * ACC_TOTAL;

    // L1 (MFMA, 2-pass)
    l1_extract<<<B, 128, 0, stream>>>(x, c, Ph, Pl, pnorm);
    l1_gemm_reduce<<<B / 2, 256, 0, stream>>>(
        Ph, Pl, W1h + (size_t)c * 4096, W1l + (size_t)c * 4096, pnorm, w1n + c * 128, accC);
    l1_fin<<<1, 64, 0, stream>>>(accC, inv36, (double)B * 100.0);
    l1_gemm_sfm<<<B / 2, 256, 0, stream>>>(
        Ph, Pl, W1h + (size_t)c * 4096, W1l + (size_t)c * 4096, pnorm, w1n + c * 128,
        inv36, cb, Xhi, Xlo, xn);

    // L2: (M2 x 128) x (256 x 128) -> dist2 (M2 x 225)
    gemm_dist_mfma<<<dim3(M2 / 128, 2), 256, 0, stream>>>(
        Xhi, Xlo, Whi2 + (size_t)c * 256 * 128, Wlo2 + (size_t)c * 256 * 128,
        xn, wn2 + c * 256, distA, 225, 128, accC, ACC_L2);
    l2_sfm<<<dim3(B, 3), 256, 0, stream>>>(distA, accC, (double)M2 * 225.0, cb, Xhi, Xlo, xn);

    // L3: (M3 x 256) x (640 x 256) -> dist3 (M3 x 625)
    gemm_dist_mfma<<<dim3(M3 / 128, 5), 256, 0, stream>>>(
        Xhi, Xlo, Whi3 + (size_t)c * 640 * 256, Wlo3 + (size_t)c * 640 * 256,
        xn, wn3 + c * 640, distA, 625, 256, accC, ACC_L3);
    l3_sfm<<<B, 256, 0, stream>>>(distA, accC, (double)M3 * 625.0, cb, Xhi, Xlo, xn);

    // L4: (B x 640) x (1280 x 640) -> dist4 (B x 1225)
    gemm_dist_mfma<<<dim3(B / 128, 10), 256, 0, stream>>>(
        Xhi, Xlo, Whi4 + (size_t)c * 1280 * 640, Wlo4 + (size_t)c * 1280 * 640,
        xn, wn4 + c * 1280, distA, 1225, 640, accC, ACC_L4);
    fc_acc<<<B, 128, 0, stream>>>(distA, accC, (double)B * 1225.0, cb, fcw, fcb, out, c);
  }
}

// Round 4
// 780.397 us; speedup vs baseline: 1.8445x; 1.2327x over previous
//
#include <hip/hip_runtime.h>

// SOMNetwork forward. All four rbf/cdist layers via split-bf16 MFMA GEMM
// (hi/lo decomposition, 3 MFMAs/product). L1: padded patch matrix (64 rows/img,
// K=32), two-pass GEMM: pass A -> per-block float partials (NO global atomics)
// + l1_part_fin f64 reduce; pass B fused exp/crelu/2x2-alpha-pool epilogue
// via LDS pair-sums. L2/L3/L4 std partials via 1 f64 atomic pair per block;
// finalize folded into consumer preambles.

typedef unsigned short u16;
typedef short bf16x8 __attribute__((ext_vector_type(8)));
typedef float f32x4 __attribute__((ext_vector_type(4)));

#define STRIPES 64
#define ACC_L2 0            // 64 stripes * 2 doubles per layer region
#define ACC_L3 128
#define ACC_L4 256
#define ACC_TOTAL 384
#define ESM_P 132           // padded psm row

__device__ __forceinline__ u16 f2bf(float f) {
  unsigned int u = __float_as_uint(f);
  unsigned int r = (u + 0x7fffu + ((u >> 16) & 1u)) >> 16;
  return (u16)r;
}
__device__ __forceinline__ float bf2f(u16 h) {
  return __uint_as_float(((unsigned int)h) << 16);
}
__device__ __forceinline__ void gload16(const void* g, const void* l) {
  __builtin_amdgcn_global_load_lds(
      (const __attribute__((address_space(1))) unsigned int*)g,
      (__attribute__((address_space(3))) unsigned int*)l, 16, 0, 0);
}

__global__ void zero_acc_kernel(double* __restrict__ acc, int n) {
  int i = blockIdx.x * blockDim.x + threadIdx.x;
  if (i < n) acc[i] = 0.0;
}

// ---------------- weight prep: fp32 -> hi/lo bf16 (padded) + row norms ----------------
__global__ __launch_bounds__(128) void w_prep(
    const float* __restrict__ W, int O, int K, int Opad, int Kp,
    u16* __restrict__ hi, u16* __restrict__ lo, float* __restrict__ wn)
{
  __shared__ float red[2];
  int o = blockIdx.x, cc = blockIdx.y, t = threadIdx.x;
  const float* src = W + ((size_t)cc * O + o) * K;
  u16* dh = hi + ((size_t)cc * Opad + o) * Kp;
  u16* dl = lo + ((size_t)cc * Opad + o) * Kp;
  float p = 0.f;
  for (int k = t; k < Kp; k += 128) {
    float v = (o < O && k < K) ? src[k] : 0.f;
    u16 h = f2bf(v);
    u16 l = f2bf(v - bf2f(h));
    dh[k] = h; dl[k] = l;
    p = fmaf(v, v, p);
  }
  for (int off = 32; off; off >>= 1) p += __shfl_down(p, off, 64);
  if ((t & 63) == 0) red[t >> 6] = p;
  __syncthreads();
  if (t == 0) wn[(size_t)cc * Opad + o] = red[0] + red[1];
}

// ---------------- L1 patch extraction: (B images) -> P (B*64 x 32) hi/lo + pnorm ----------------
__global__ __launch_bounds__(128) void l1_extract(
    const float* __restrict__ x, int c,
    u16* __restrict__ Ph, u16* __restrict__ Pl, float* __restrict__ pnorm)
{
  __shared__ float img[784];
  int b = blockIdx.x, t = threadIdx.x;
  const float4* xim = (const float4*)(x + ((size_t)b * 3 + c) * 784);
  ((float4*)img)[t] = xim[t];
  if (t < 68) ((float4*)img)[128 + t] = xim[128 + t];
  __syncthreads();
  size_t base = (size_t)b * 64;
  int kk = t & 31, sub = t >> 5;
#pragma unroll
  for (int it = 0; it < 16; ++it) {
    int row = it * 4 + sub;
    float val = 0.f;
    if (row < 36 && kk < 25) {
      int pi = row / 6, pj = row - pi * 6;
      int r = kk / 5, s = kk - r * 5;
      val = img[(pi * 4 + r) * 28 + pj * 4 + s];
    }
    u16 h = f2bf(val);
    u16 l = f2bf(val - bf2f(h));
    Ph[(base + row) * 32 + kk] = h;
    Pl[(base + row) * 32 + kk] = l;
    float p = val * val;
    p += __shfl_down(p, 16, 32);
    p += __shfl_down(p, 8, 32);
    p += __shfl_down(p, 4, 32);
    p += __shfl_down(p, 2, 32);
    p += __shfl_down(p, 1, 32);
    if (kk == 0) pnorm[base + row] = p;
  }
}

// ---------------- shared L1 GEMM mainloop (M tile 128, O=128, K=32, 1 staging step) ----------------
#define L1_MAINLOOP(Ph, Pl, Wh, Wl, m0, sm, accv)                              \
  {                                                                            \
    u16* smAh = sm; u16* smAl = sm + 4096;                                     \
    u16* smBh = sm + 8192; u16* smBl = sm + 12288;                             \
    const int t_ = threadIdx.x;                                                \
    const int w_ = t_ >> 6, lane_ = t_ & 63;                                   \
    const int kk_ = w_ * 8;                                                    \
    _Pragma("unroll")                                                          \
    for (int u = 0; u < 2; ++u) {                                              \
      const size_t ga = (size_t)(m0 + u * 64 + lane_) * 32 + kk_;              \
      const size_t gb = (size_t)(u * 64 + lane_) * 32 + kk_;                   \
      const int ls = (w_ * 128 + u * 64) * 8;                                  \
      gload16(Ph + ga, smAh + ls); gload16(Pl + ga, smAl + ls);                \
      gload16(Wh + gb, smBh + ls); gload16(Wl + gb, smBl + ls);                \
    }                                                                          \
    asm volatile("s_waitcnt vmcnt(0)" ::: "memory");                           \
    __syncthreads();                                                           \
    const int wr_ = w_ >> 1, wc_ = w_ & 1;                                     \
    const int q4_ = lane_ >> 4, r16_ = lane_ & 15;                             \
    bf16x8 Ah[4], Al[4], Bh[4], Bl[4];                                         \
    _Pragma("unroll")                                                          \
    for (int i = 0; i < 4; ++i) {                                              \
      int ao = (q4_ * 128 + wr_ * 64 + i * 16 + r16_) * 8;                     \
      int bo = (q4_ * 128 + wc_ * 64 + i * 16 + r16_) * 8;                     \
      Ah[i] = *(const bf16x8*)(smAh + ao);                                     \
      Al[i] = *(const bf16x8*)(smAl + ao);                                     \
      Bh[i] = *(const bf16x8*)(smBh + bo);                                     \
      Bl[i] = *(const bf16x8*)(smBl + bo);                                     \
    }                                                                          \
    _Pragma("unroll")                                                          \
    for (int i = 0; i < 4; ++i)                                                \
      _Pragma("unroll")                                                        \
      for (int j = 0; j < 4; ++j) {                                            \
        accv[i][j] = __builtin_amdgcn_mfma_f32_16x16x32_bf16(Ah[i], Bh[j], accv[i][j], 0, 0, 0); \
        accv[i][j] = __builtin_amdgcn_mfma_f32_16x16x32_bf16(Al[i], Bh[j], accv[i][j], 0, 0, 0); \
        accv[i][j] = __builtin_amdgcn_mfma_f32_16x16x32_bf16(Ah[i], Bl[j], accv[i][j], 0, 0, 0); \
      }                                                                        \
  }

// ---------------- L1 GEMM pass A: per-position s/q -> per-block float partials ----------------
__global__ __launch_bounds__(256) void l1_gemm_reduce(
    const u16* __restrict__ Ph, const u16* __restrict__ Pl,
    const u16* __restrict__ Wh, const u16* __restrict__ Wl,
    const float* __restrict__ pnorm, const float* __restrict__ wn,
    float* __restrict__ part, int NB)
{
  __shared__ __align__(16) u16 sm[16384];
  __shared__ float sq[72];
  int t = threadIdx.x;
  if (t < 72) sq[t] = 0.f;
  f32x4 accv[4][4];
#pragma unroll
  for (int i = 0; i < 4; ++i)
#pragma unroll
    for (int j = 0; j < 4; ++j) accv[i][j] = (f32x4){0.f, 0.f, 0.f, 0.f};
  const int m0 = blockIdx.x * 128;
  L1_MAINLOOP(Ph, Pl, Wh, Wl, m0, sm, accv);   // internal barrier orders sq init

  const int w = t >> 6, lane = t & 63;
  const int wr = w >> 1, wc = w & 1, q4 = lane >> 4, r16 = lane & 15;
#pragma unroll
  for (int i = 0; i < 4; ++i) {
#pragma unroll
    for (int r = 0; r < 4; ++r) {
      int pos = i * 16 + q4 * 4 + r;
      if (pos < 36) {
        float pn = pnorm[m0 + wr * 64 + pos];
        float s = 0.f, q = 0.f;
#pragma unroll
        for (int j = 0; j < 4; ++j) {
          int col = wc * 64 + j * 16 + r16;
          if (col < 100) {
            float d2 = pn + wn[col] - 2.f * accv[i][j][r];
            float d2c = fmaxf(d2, 0.f) + 1e-12f;
            s += sqrtf(d2c);
            q += d2c;
          }
        }
        s += __shfl_down(s, 8, 16);
        s += __shfl_down(s, 4, 16);
        s += __shfl_down(s, 2, 16);
        s += __shfl_down(s, 1, 16);
        q += __shfl_down(q, 8, 16);
        q += __shfl_down(q, 4, 16);
        q += __shfl_down(q, 2, 16);
        q += __shfl_down(q, 1, 16);
        if (r16 == 0) {
          atomicAdd(&sq[pos], s);        // LDS atomics only
          atomicAdd(&sq[36 + pos], q);
        }
      }
    }
  }
  __syncthreads();
  if (t < 72) part[(size_t)t * NB + blockIdx.x] = sq[t];
}

// reduce per-block partials -> inv36 (f64)
__global__ __launch_bounds__(256) void l1_part_fin(
    const float* __restrict__ part, int NB, float* __restrict__ inv36, double n)
{
  __shared__ double sh[8];
  int pos = blockIdx.x, t = threadIdx.x;
  double s = 0.0, q = 0.0;
  for (int b = t; b < NB; b += 256) {
    s += part[(size_t)pos * NB + b];
    q += part[(size_t)(36 + pos) * NB + b];
  }
  for (int off = 32; off; off >>= 1) {
    s += __shfl_down(s, off, 64);
    q += __shfl_down(q, off, 64);
  }
  if ((t & 63) == 0) { sh[(t >> 6) * 2] = s; sh[(t >> 6) * 2 + 1] = q; }
  __syncthreads();
  if (t == 0) {
    s = sh[0] + sh[2] + sh[4] + sh[6];
    q = sh[1] + sh[3] + sh[5] + sh[7];
    double var = (q - s * s / n) / (n - 1.0);
    inv36[pos] = var > 0.0 ? (float)(0.5 / var) : __builtin_inff();
  }
}

// ---------------- L1 GEMM pass B: fused exp/crelu/2x2-alpha-pool epilogue ----------------
__global__ __launch_bounds__(256) void l1_gemm_sfm(
    const u16* __restrict__ Ph, const u16* __restrict__ Pl,
    const u16* __restrict__ Wh, const u16* __restrict__ Wl,
    const float* __restrict__ pnorm, const float* __restrict__ wn,
    const float* __restrict__ inv36, const float* __restrict__ cb,
    u16* __restrict__ Xhi, u16* __restrict__ Xlo, float* __restrict__ xn)
{
  __shared__ __align__(16) u16 sm[16384];
  __shared__ float psm[2 * 18 * ESM_P];   // 2x2-pool row-pair sums
  __shared__ float inv_s[36];
  int t = threadIdx.x;
  if (t < 36) inv_s[t] = inv36[t];
  f32x4 accv[4][4];
#pragma unroll
  for (int i = 0; i < 4; ++i)
#pragma unroll
    for (int j = 0; j < 4; ++j) accv[i][j] = (f32x4){0.f, 0.f, 0.f, 0.f};
  const int m0 = blockIdx.x * 128;
  L1_MAINLOOP(Ph, Pl, Wh, Wl, m0, sm, accv);

  const float bias = cb[0];
  const int w = t >> 6, lane = t & 63;
  const int wr = w >> 1, wc = w & 1, q4 = lane >> 4, r16 = lane & 15;
#pragma unroll
  for (int i = 0; i < 4; ++i) {
#pragma unroll
    for (int j = 0; j < 4; ++j) {
      int col = wc * 64 + j * 16 + r16;
      float e[4];
#pragma unroll
      for (int r = 0; r < 4; ++r) {
        int pos = i * 16 + q4 * 4 + r;
        float ev = 0.f;
        if (pos < 36) {
          float pn = pnorm[m0 + wr * 64 + pos];
          float d2 = pn + wn[col] - 2.f * accv[i][j][r];
          float d2c = fmaxf(d2, 0.f) + 1e-12f;
          ev = expf(-d2c * inv_s[pos]);
          ev = (ev >= bias) ? ev : 0.f;
        }
        e[r] = ev;
      }
#pragma unroll
      for (int k = 0; k < 2; ++k) {
        int p = i * 8 + q4 * 2 + k;
        if (p < 18) {
          bool top = ((p / 3) & 1) == 0;
          float c = top ? fmaf(0.729f, e[2 * k], 0.81f * e[2 * k + 1])
                        : fmaf(0.9f, e[2 * k], e[2 * k + 1]);
          psm[(wr * 18 + p) * ESM_P + col] = c;
        }
      }
    }
  }
  __syncthreads();

  size_t b0 = (size_t)blockIdx.x * 2;   // first image of the pair
#pragma unroll
  for (int it = 0; it < 5; ++it) {
    int idx = t + 256 * it;
    if (idx >= 1152) break;
    int rowp = idx >> 6;        // 0..17 = im*9 + IJ  (one rowp per wave-iter)
    int cp = idx & 63;
    int im = rowp / 9, IJ = rowp - im * 9;
    int I = IJ / 3, J = IJ - I * 3;
    const float* basep = &psm[(im * 18 + 6 * I + J) * ESM_P];
    int col0 = 2 * cp, col1 = 2 * cp + 1;
    float v0 = (col0 < 100) ? 0.25f * (basep[col0] + basep[3 * ESM_P + col0]) : 0.f;
    float v1 = (col1 < 100) ? 0.25f * (basep[col1] + basep[3 * ESM_P + col1]) : 0.f;
    u16 h0 = f2bf(v0), h1 = f2bf(v1);
    u16 l0 = f2bf(v0 - bf2f(h0)), l1 = f2bf(v1 - bf2f(h1));
    size_t xrow = b0 * 9 + rowp;
    *(unsigned int*)&Xhi[xrow * 128 + col0] = (unsigned int)h0 | ((unsigned int)h1 << 16);
    *(unsigned int*)&Xlo[xrow * 128 + col0] = (unsigned int)l0 | ((unsigned int)l1 << 16);
    float p = fmaf(v0, v0, v1 * v1);
    for (int off = 32; off; off >>= 1) p += __shfl_down(p, off, 64);
    if ((t & 63) == 0) xn[xrow] = p;    // each rowp owned by exactly one wave-iter
  }
}

// ---------------- split-bf16 MFMA cdist GEMM (L2/L3/L4), fused s/q reduce ----------------
__global__ __launch_bounds__(256) void gemm_dist_mfma(
    const u16* __restrict__ Xhi, const u16* __restrict__ Xlo,
    const u16* __restrict__ Whi, const u16* __restrict__ Wlo,
    const float* __restrict__ xn, const float* __restrict__ wn,
    float* __restrict__ dist, int O, int Kp,
    double* __restrict__ acc, int accbase)
{
  __shared__ __align__(16) u16 sm[4 * 4096];
  __shared__ double redsm[8];
  u16* smAh = sm;
  u16* smAl = sm + 4096;
  u16* smBh = sm + 8192;
  u16* smBl = sm + 12288;

  const int t = threadIdx.x;
  const int w = t >> 6, lane = t & 63;
  const int wr = w >> 1, wc = w & 1;
  const int m0 = blockIdx.x * 128, o0 = blockIdx.y * 128;
  const int q4 = lane >> 4, r16 = lane & 15;

  f32x4 accv[4][4];
#pragma unroll
  for (int i = 0; i < 4; ++i)
#pragma unroll
    for (int j = 0; j < 4; ++j) accv[i][j] = (f32x4){0.f, 0.f, 0.f, 0.f};

  int aoff[4], boff[4];
#pragma unroll
  for (int i = 0; i < 4; ++i) {
    aoff[i] = (q4 * 128 + wr * 64 + i * 16 + r16) * 8;
    boff[i] = (q4 * 128 + wc * 64 + i * 16 + r16) * 8;
  }

  for (int k0 = 0; k0 < Kp; k0 += 32) {
    const int kk = k0 + w * 8;
#pragma unroll
    for (int u = 0; u < 2; ++u) {
      const size_t ga = (size_t)(m0 + u * 64 + lane) * Kp + kk;
      const size_t gb = (size_t)(o0 + u * 64 + lane) * Kp + kk;
      const int ls = (w * 128 + u * 64) * 8;
      gload16(Xhi + ga, smAh + ls);
      gload16(Xlo + ga, smAl + ls);
      gload16(Whi + gb, smBh + ls);
      gload16(Wlo + gb, smBl + ls);
    }
    asm volatile("s_waitcnt vmcnt(0)" ::: "memory");
    __syncthreads();

    bf16x8 Ah[4], Al[4], Bh[4], Bl[4];
#pragma unroll
    for (int i = 0; i < 4; ++i) {
      Ah[i] = *(const bf16x8*)(smAh + aoff[i]);
      Al[i] = *(const bf16x8*)(smAl + aoff[i]);
      Bh[i] = *(const bf16x8*)(smBh + boff[i]);
      Bl[i] = *(const bf16x8*)(smBl + boff[i]);
    }
#pragma unroll
    for (int i = 0; i < 4; ++i)
#pragma unroll
      for (int j = 0; j < 4; ++j) {
        accv[i][j] = __builtin_amdgcn_mfma_f32_16x16x32_bf16(Ah[i], Bh[j], accv[i][j], 0, 0, 0);
        accv[i][j] = __builtin_amdgcn_mfma_f32_16x16x32_bf16(Al[i], Bh[j], accv[i][j], 0, 0, 0);
        accv[i][j] = __builtin_amdgcn_mfma_f32_16x16x32_bf16(Ah[i], Bl[j], accv[i][j], 0, 0, 0);
      }
    __syncthreads();
  }

  double s = 0.0, qd = 0.0;
#pragma unroll
  for (int i = 0; i < 4; ++i) {
    const int mb = m0 + wr * 64 + i * 16 + q4 * 4;
    float xnv[4];
#pragma unroll
    for (int r = 0; r < 4; ++r) xnv[r] = xn[mb + r];
#pragma unroll
    for (int j = 0; j < 4; ++j) {
      const int o = o0 + wc * 64 + j * 16 + r16;
      if (o < O) {
        const float wnv = wn[o];
#pragma unroll
        for (int r = 0; r < 4; ++r) {
          float d2 = xnv[r] + wnv - 2.f * accv[i][j][r];
          float d = sqrtf(fmaxf(d2, 0.f) + 1e-12f);
          dist[(size_t)(mb + r) * O + o] = d;
          s += d; qd += (double)d * d;
        }
      }
    }
  }
  for (int off = 32; off; off >>= 1) {
    s += __shfl_down(s, off, 64);
    qd += __shfl_down(qd, off, 64);
  }
  if (lane == 0) { redsm[w * 2] = s; redsm[w * 2 + 1] = qd; }
  __syncthreads();
  if (t == 0) {
    s = redsm[0] + redsm[2] + redsm[4] + redsm[6];
    qd = redsm[1] + redsm[3] + redsm[5] + redsm[7];
    int stripe = (blockIdx.x + blockIdx.y * gridDim.x) & (STRIPES - 1);
    atomicAdd(&acc[accbase + stripe * 2], s);
    atomicAdd(&acc[accbase + stripe * 2 + 1], qd);
  }
}

// block preamble: reduce 64-stripe acc -> inv = 0.5/var, broadcast via LDS
__device__ __forceinline__ float block_inv_from_acc(
    const double* __restrict__ acc, int base, double n, float* sh)
{
  int t = threadIdx.x;
  if (t < 64) {
    double s = acc[base + 2 * t], q = acc[base + 2 * t + 1];
    for (int off = 32; off; off >>= 1) {
      s += __shfl_down(s, off, 64);
      q += __shfl_down(q, off, 64);
    }
    if (t == 0) {
      double var = (q - s * s / n) / (n - 1.0);
      *sh = var > 0.0 ? (float)(0.5 / var) : __builtin_inff();
    }
  }
  __syncthreads();
  return *sh;
}

// exp -> crelu(cb1) -> [0.81,0.9,1]/3 pool -> hi/lo (Kp=256) + xn
__global__ __launch_bounds__(256) void l2_sfm(
    const float* __restrict__ dist2, const double* __restrict__ acc, double n,
    const float* __restrict__ cb, u16* __restrict__ Xhi, u16* __restrict__ Xlo,
    float* __restrict__ xn)
{
  __shared__ float shinv;
  __shared__ float red[4];
  float inv = block_inv_from_acc(acc, ACC_L2, n, &shinv);
  int b = blockIdx.x, u = blockIdx.y, ch = threadIdx.x;
  float bias = cb[1];
  float v = 0.f;
  if (ch < 225) {
    const float av[3] = {0.81f, 0.9f, 1.0f};
    float a = 0.f;
#pragma unroll
    for (int vv = 0; vv < 3; ++vv) {
      float d = dist2[((size_t)b * 9 + u * 3 + vv) * 225 + ch];
      float e = expf(-d * d * inv);
      e = (e >= bias) ? e : 0.f;
      a = fmaf(e, av[vv], a);
    }
    v = a * (1.f / 3.f);
  }
  size_t row = (size_t)b * 3 + u;
  u16 h = f2bf(v);
  u16 l = f2bf(v - bf2f(h));
  Xhi[row * 256 + ch] = h;
  Xlo[row * 256 + ch] = l;
  float p = v * v;
  for (int off = 32; off; off >>= 1) p += __shfl_down(p, off, 64);
  if ((ch & 63) == 0) red[ch >> 6] = p;
  __syncthreads();
  if (ch == 0) xn[row] = red[0] + red[1] + red[2] + red[3];
}

// exp -> crelu(cb2) -> [0.81,0.9,1]/3 pool -> hi/lo (Kp=640) + xn
__global__ __launch_bounds__(256) void l3_sfm(
    const float* __restrict__ dist3, const double* __restrict__ acc, double n,
    const float* __restrict__ cb, u16* __restrict__ Xhi, u16* __restrict__ Xlo,
    float* __restrict__ xn)
{
  __shared__ float shinv;
  __shared__ float red[4];
  float inv = block_inv_from_acc(acc, ACC_L3, n, &shinv);
  int b = blockIdx.x, t = threadIdx.x;
  float bias = cb[2];
  const float au[3] = {0.81f, 0.9f, 1.0f};
  float p = 0.f;
  for (int ch = t; ch < 640; ch += 256) {
    float v = 0.f;
    if (ch < 625) {
      float a = 0.f;
#pragma unroll
      for (int u = 0; u < 3; ++u) {
        float d = dist3[((size_t)b * 3 + u) * 625 + ch];
        float e = expf(-d * d * inv);
        e = (e >= bias) ? e : 0.f;
        a = fmaf(e, au[u], a);
      }
      v = a * (1.f / 3.f);
    }
    u16 h = f2bf(v);
    u16 l = f2bf(v - bf2f(h));
    Xhi[(size_t)b * 640 + ch] = h;
    Xlo[(size_t)b * 640 + ch] = l;
    p = fmaf(v, v, p);
  }
  for (int off = 32; off; off >>= 1) p += __shfl_down(p, off, 64);
  if ((t & 63) == 0) red[t >> 6] = p;
  __syncthreads();
  if (t == 0) xn[b] = red[0] + red[1] + red[2] + red[3];
}

// L4 exp/crelu fused into FC: out[b,:] (+)= act(dist4[b,:]) @ fcw_c^T (+fcb on c==0)
__global__ __launch_bounds__(128) void fc_acc(
    const float* __restrict__ dist4, const double* __restrict__ acc, double n,
    const float* __restrict__ cb, const float* __restrict__ fcw,
    const float* __restrict__ fcb, float* __restrict__ out, int c)
{
  __shared__ float shinv;
  float inv = block_inv_from_acc(acc, ACC_L4, n, &shinv);
  int b = blockIdx.x, t = threadIdx.x;
  float bias = cb[3];
  float p[10];
#pragma unroll
  for (int k = 0; k < 10; ++k) p[k] = 0.f;
  for (int j = t; j < 1225; j += 128) {
    float d = dist4[(size_t)b * 1225 + j];
    float v = expf(-d * d * inv);
    v = (v >= bias) ? v : 0.f;
#pragma unroll
    for (int k = 0; k < 10; ++k) p[k] = fmaf(v, fcw[k * 3675 + c * 1225 + j], p[k]);
  }
#pragma unroll
  for (int k = 0; k < 10; ++k)
    for (int off = 32; off; off >>= 1) p[k] += __shfl_down(p[k], off, 64);
  __shared__ float red[2][10];
  int wave = t >> 6;
  if ((t & 63) == 0) {
#pragma unroll
    for (int k = 0; k < 10; ++k) red[wave][k] = p[k];
  }
  __syncthreads();
  if (t < 10) {
    float v = red[0][t] + red[1][t];
    if (c == 0) out[(size_t)b * 10 + t] = fcb[t] + v;
    else        out[(size_t)b * 10 + t] += v;
  }
}

extern "C" void kernel_launch(void* const* d_in, const int* in_sizes, int n_in,
                              void* d_out, int out_size, void* d_ws, size_t ws_size,
                              hipStream_t stream) {
  const float* x   = (const float*)d_in[0];
  const float* w1  = (const float*)d_in[1];
  const float* w2  = (const float*)d_in[2];
  const float* w3  = (const float*)d_in[3];
  const float* w4  = (const float*)d_in[4];
  const float* fcw = (const float*)d_in[5];
  const float* fcb = (const float*)d_in[6];
  const float* cb  = (const float*)d_in[7];
  float* out = (float*)d_out;
  int B = in_sizes[0] / (3 * 28 * 28);   // 4096
  int M2 = B * 9, M3 = B * 3;
  int NB = B / 2;                        // l1 gemm blocks

  // workspace layout
  char* p = (char*)d_ws;
  u16* Ph = (u16*)p;                         // B*64*32 u16 = 16.78 MB
  u16* Pl = Ph + (size_t)B * 64 * 32;        // region1 total 33.55 MB,
  float* distA = (float*)Ph;                 //   aliased with dist2/3/4 (<=33.2 MB)
  char* q = p + (size_t)B * 64 * 32 * 2 * 2;
  u16* Xhi = (u16*)q;                        // 36864*128 u16 = 9.44 MB
  u16* Xlo = Xhi + (size_t)M2 * 128;
  u16* Whi = Xlo + (size_t)M2 * 128;         // 3*(256*128+640*256+1280*640) u16
  u16* Wlo = Whi + 3047424;
  u16* W1h = Wlo + 3047424;                  // 3*128*32
  u16* W1l = W1h + 12288;
  float* wn  = (float*)(W1l + 12288);        // 6528
  float* w1n = wn + 6528;                    // 384
  float* pnorm = w1n + 384;                  // B*64
  float* xn = pnorm + (size_t)B * 64;        // M2
  float* inv36 = xn + M2;                    // 64
  double* accd = (double*)(inv36 + 64);      // 3*ACC_TOTAL
  float* part = (float*)(accd + 3 * ACC_TOTAL);  // 72*NB floats
  u16* Whi2 = Whi;            u16* Wlo2 = Wlo;            float* wn2 = wn;
  u16* Whi3 = Whi + 98304;    u16* Wlo3 = Wlo + 98304;    float* wn3 = wn + 768;
  u16* Whi4 = Whi + 589824;   u16* Wlo4 = Wlo + 589824;   float* wn4 = wn + 2688;

  // upfront: zero acc, prep all weights
  zero_acc_kernel<<<(3 * ACC_TOTAL + 255) / 256, 256, 0, stream>>>(accd, 3 * ACC_TOTAL);
  w_prep<<<dim3(128, 3),  128, 0, stream>>>(w1, 100, 25,  128, 32,  W1h,  W1l,  w1n);
  w_prep<<<dim3(256, 3),  128, 0, stream>>>(w2, 225, 100, 256, 128, Whi2, Wlo2, wn2);
  w_prep<<<dim3(640, 3),  128, 0, stream>>>(w3, 625, 225, 640, 256, Whi3, Wlo3, wn3);
  w_prep<<<dim3(1280, 3), 128, 0, stream>>>(w4, 1225, 625, 1280, 640, Whi4, Wlo4, wn4);

  for (int c = 0; c < 3; ++c) {
    double* accC = accd + (size_t)c * ACC_TOTAL;

    // L1 (MFMA, 2-pass, no global atomics)
    l1_extract<<<B, 128, 0, stream>>>(x, c, Ph, Pl, pnorm);
    l1_gemm_reduce<<<NB, 256, 0, stream>>>(
        Ph, Pl, W1h + (size_t)c * 4096, W1l + (size_t)c * 4096, pnorm, w1n + c * 128,
        part, NB);
    l1_part_fin<<<36, 256, 0, stream>>>(part, NB, inv36, (double)B * 100.0);
    l1_gemm_sfm<<<NB, 256, 0, stream>>>(
        Ph, Pl, W1h + (size_t)c * 4096, W1l + (size_t)c * 4096, pnorm, w1n + c * 128,
        inv36, cb, Xhi, Xlo, xn);

    // L2: (M2 x 128) x (256 x 128) -> dist2 (M2 x 225)
    gemm_dist_mfma<<<dim3(M2 / 128, 2), 256, 0, stream>>>(
        Xhi, Xlo, Whi2 + (size_t)c * 256 * 128, Wlo2 + (size_t)c * 256 * 128,
        xn, wn2 + c * 256, distA, 225, 128, accC, ACC_L2);
    l2_sfm<<<dim3(B, 3), 256, 0, stream>>>(distA, accC, (double)M2 * 225.0, cb, Xhi, Xlo, xn);

    // L3: (M3 x 256) x (640 x 256) -> dist3 (M3 x 625)
    gemm_dist_mfma<<<dim3(M3 / 128, 5), 256, 0, stream>>>(
        Xhi, Xlo, Whi3 + (size_t)c * 640 * 256, Wlo3 + (size_t)c * 640 * 256,
        xn, wn3 + c * 640, distA, 625, 256, accC, ACC_L3);
    l3_sfm<<<B, 256, 0, stream>>>(distA, accC, (double)M3 * 625.0, cb, Xhi, Xlo, xn);

    // L4: (B x 640) x (1280 x 640) -> dist4 (B x 1225)
    gemm_dist_mfma<<<dim3(B / 128, 10), 256, 0, stream>>>(
        Xhi, Xlo, Whi4 + (size_t)c * 1280 * 640, Wlo4 + (size_t)c * 1280 * 640,
        xn, wn4 + c * 1280, distA, 1225, 640, accC, ACC_L4);
    fc_acc<<<B, 128, 0, stream>>>(distA, accC, (double)B * 1225.0, cb, fcw, fcb, out, c);
  }
}

// Round 5
// 644.436 us; speedup vs baseline: 2.2336x; 1.2110x over previous
//
#include <hip/hip_runtime.h>

// SOMNetwork forward. All four rbf/cdist layers via split-bf16 MFMA GEMM
// (hi/lo decomposition, 3 MFMAs/product). Channels batched into grid z when
// ws_size allows (plan A, ~175 MB, 13 dispatches); otherwise channel-serial
// fallback (plan B, ~66 MB, 35 dispatches) using the same kernels with
// zero scratch strides.

typedef unsigned short u16;
typedef short bf16x8 __attribute__((ext_vector_type(8)));
typedef float f32x4 __attribute__((ext_vector_type(4)));

#define STRIPES 64
#define ACC_L2 0            // 64 stripes * 2 doubles per layer region
#define ACC_L3 128
#define ACC_L4 256
#define ACC_TOTAL 384
#define ESM_P 132

__device__ __forceinline__ u16 f2bf(float f) {
  unsigned int u = __float_as_uint(f);
  unsigned int r = (u + 0x7fffu + ((u >> 16) & 1u)) >> 16;
  return (u16)r;
}
__device__ __forceinline__ float bf2f(u16 h) {
  return __uint_as_float(((unsigned int)h) << 16);
}
__device__ __forceinline__ void gload16(const void* g, const void* l) {
  __builtin_amdgcn_global_load_lds(
      (const __attribute__((address_space(1))) unsigned int*)g,
      (__attribute__((address_space(3))) unsigned int*)l, 16, 0, 0);
}

__global__ void zero_acc_kernel(double* __restrict__ acc, int n) {
  int i = blockIdx.x * blockDim.x + threadIdx.x;
  if (i < n) acc[i] = 0.0;
}

// ---------------- weight prep: fp32 -> hi/lo bf16 (padded) + row norms ----------------
__global__ __launch_bounds__(128) void w_prep(
    const float* __restrict__ W, int O, int K, int Opad, int Kp,
    u16* __restrict__ hi, u16* __restrict__ lo, float* __restrict__ wn)
{
  __shared__ float red[2];
  int o = blockIdx.x, cc = blockIdx.y, t = threadIdx.x;
  const float* src = W + ((size_t)cc * O + o) * K;
  u16* dh = hi + ((size_t)cc * Opad + o) * Kp;
  u16* dl = lo + ((size_t)cc * Opad + o) * Kp;
  float p = 0.f;
  for (int k = t; k < Kp; k += 128) {
    float v = (o < O && k < K) ? src[k] : 0.f;
    u16 h = f2bf(v);
    u16 l = f2bf(v - bf2f(h));
    dh[k] = h; dl[k] = l;
    p = fmaf(v, v, p);
  }
  for (int off = 32; off; off >>= 1) p += __shfl_down(p, off, 64);
  if ((t & 63) == 0) red[t >> 6] = p;
  __syncthreads();
  if (t == 0) wn[(size_t)cc * Opad + o] = red[0] + red[1];
}

// ---------------- L1 patch extraction ----------------
__global__ __launch_bounds__(128) void l1_extract(
    const float* __restrict__ x, int c0,
    u16* __restrict__ Ph, u16* __restrict__ Pl, float* __restrict__ pnorm,
    int sPc, int sPnc)
{
  __shared__ float img[784];
  int b = blockIdx.x, zi = blockIdx.y, t = threadIdx.x;
  int c = c0 + zi;
  Ph += (size_t)zi * sPc; Pl += (size_t)zi * sPc; pnorm += (size_t)zi * sPnc;
  const float4* xim = (const float4*)(x + ((size_t)b * 3 + c) * 784);
  ((float4*)img)[t] = xim[t];
  if (t < 68) ((float4*)img)[128 + t] = xim[128 + t];
  __syncthreads();
  size_t base = (size_t)b * 64;
  int kk = t & 31, sub = t >> 5;
#pragma unroll
  for (int it = 0; it < 16; ++it) {
    int row = it * 4 + sub;
    float val = 0.f;
    if (row < 36 && kk < 25) {
      int pi = row / 6, pj = row - pi * 6;
      int r = kk / 5, s = kk - r * 5;
      val = img[(pi * 4 + r) * 28 + pj * 4 + s];
    }
    u16 h = f2bf(val);
    u16 l = f2bf(val - bf2f(h));
    Ph[(base + row) * 32 + kk] = h;
    Pl[(base + row) * 32 + kk] = l;
    float p = val * val;
    p += __shfl_down(p, 16, 32);
    p += __shfl_down(p, 8, 32);
    p += __shfl_down(p, 4, 32);
    p += __shfl_down(p, 2, 32);
    p += __shfl_down(p, 1, 32);
    if (kk == 0) pnorm[base + row] = p;
  }
}

// ---------------- shared L1 GEMM mainloop (M tile 128, O=128, K=32) ----------------
#define L1_MAINLOOP(Ph, Pl, Wh, Wl, m0, sm, accv)                              \
  {                                                                            \
    u16* smAh = sm; u16* smAl = sm + 4096;                                     \
    u16* smBh = sm + 8192; u16* smBl = sm + 12288;                             \
    const int t_ = threadIdx.x;                                                \
    const int w_ = t_ >> 6, lane_ = t_ & 63;                                   \
    const int kk_ = w_ * 8;                                                    \
    _Pragma("unroll")                                                          \
    for (int u = 0; u < 2; ++u) {                                              \
      const size_t ga = (size_t)(m0 + u * 64 + lane_) * 32 + kk_;              \
      const size_t gb = (size_t)(u * 64 + lane_) * 32 + kk_;                   \
      const int ls = (w_ * 128 + u * 64) * 8;                                  \
      gload16(Ph + ga, smAh + ls); gload16(Pl + ga, smAl + ls);                \
      gload16(Wh + gb, smBh + ls); gload16(Wl + gb, smBl + ls);                \
    }                                                                          \
    asm volatile("s_waitcnt vmcnt(0)" ::: "memory");                           \
    __syncthreads();                                                           \
    const int wr_ = w_ >> 1, wc_ = w_ & 1;                                     \
    const int q4_ = lane_ >> 4, r16_ = lane_ & 15;                             \
    bf16x8 Ah[4], Al[4], Bh[4], Bl[4];                                         \
    _Pragma("unroll")                                                          \
    for (int i = 0; i < 4; ++i) {                                              \
      int ao = (q4_ * 128 + wr_ * 64 + i * 16 + r16_) * 8;                     \
      int bo = (q4_ * 128 + wc_ * 64 + i * 16 + r16_) * 8;                     \
      Ah[i] = *(const bf16x8*)(smAh + ao);                                     \
      Al[i] = *(const bf16x8*)(smAl + ao);                                     \
      Bh[i] = *(const bf16x8*)(smBh + bo);                                     \
      Bl[i] = *(const bf16x8*)(smBl + bo);                                     \
    }                                                                          \
    _Pragma("unroll")                                                          \
    for (int i = 0; i < 4; ++i)                                                \
      _Pragma("unroll")                                                        \
      for (int j = 0; j < 4; ++j) {                                            \
        accv[i][j] = __builtin_amdgcn_mfma_f32_16x16x32_bf16(Ah[i], Bh[j], accv[i][j], 0, 0, 0); \
        accv[i][j] = __builtin_amdgcn_mfma_f32_16x16x32_bf16(Al[i], Bh[j], accv[i][j], 0, 0, 0); \
        accv[i][j] = __builtin_amdgcn_mfma_f32_16x16x32_bf16(Ah[i], Bl[j], accv[i][j], 0, 0, 0); \
      }                                                                        \
  }

// ---------------- L1 GEMM pass A: per-position s/q -> per-block float partials ----------------
__global__ __launch_bounds__(256) void l1_gemm_reduce(
    const u16* __restrict__ Ph, const u16* __restrict__ Pl,
    const u16* __restrict__ W1h, const u16* __restrict__ W1l,
    const float* __restrict__ pnorm, const float* __restrict__ w1n,
    float* __restrict__ part, int NB, int c0,
    int sPc, int sPnc, int sPartc)
{
  __shared__ __align__(16) u16 sm[16384];
  __shared__ float sq[72];
  int t = threadIdx.x, zi = blockIdx.y, c = c0 + zi;
  Ph += (size_t)zi * sPc; Pl += (size_t)zi * sPc;
  const u16* Wh = W1h + (size_t)c * 4096;
  const u16* Wl = W1l + (size_t)c * 4096;
  pnorm += (size_t)zi * sPnc;
  const float* wn = w1n + (size_t)c * 128;
  part += (size_t)zi * sPartc;
  if (t < 72) sq[t] = 0.f;
  f32x4 accv[4][4];
#pragma unroll
  for (int i = 0; i < 4; ++i)
#pragma unroll
    for (int j = 0; j < 4; ++j) accv[i][j] = (f32x4){0.f, 0.f, 0.f, 0.f};
  const int m0 = blockIdx.x * 128;
  L1_MAINLOOP(Ph, Pl, Wh, Wl, m0, sm, accv);   // internal barrier orders sq init

  const int w = t >> 6, lane = t & 63;
  const int wr = w >> 1, wc = w & 1, q4 = lane >> 4, r16 = lane & 15;
#pragma unroll
  for (int i = 0; i < 4; ++i) {
#pragma unroll
    for (int r = 0; r < 4; ++r) {
      int pos = i * 16 + q4 * 4 + r;
      if (pos < 36) {
        float pn = pnorm[m0 + wr * 64 + pos];
        float s = 0.f, q = 0.f;
#pragma unroll
        for (int j = 0; j < 4; ++j) {
          int col = wc * 64 + j * 16 + r16;
          if (col < 100) {
            float d2 = pn + wn[col] - 2.f * accv[i][j][r];
            float d2c = fmaxf(d2, 0.f) + 1e-12f;
            s += sqrtf(d2c);
            q += d2c;
          }
        }
        s += __shfl_down(s, 8, 16);
        s += __shfl_down(s, 4, 16);
        s += __shfl_down(s, 2, 16);
        s += __shfl_down(s, 1, 16);
        q += __shfl_down(q, 8, 16);
        q += __shfl_down(q, 4, 16);
        q += __shfl_down(q, 2, 16);
        q += __shfl_down(q, 1, 16);
        if (r16 == 0) {
          atomicAdd(&sq[pos], s);
          atomicAdd(&sq[36 + pos], q);
        }
      }
    }
  }
  __syncthreads();
  if (t < 72) part[(size_t)t * NB + blockIdx.x] = sq[t];
}

__global__ __launch_bounds__(256) void l1_part_fin(
    const float* __restrict__ part, int NB, float* __restrict__ inv36, double n,
    int sPartc, int sInvc)
{
  __shared__ double sh[8];
  int pos = blockIdx.x, zi = blockIdx.y, t = threadIdx.x;
  part += (size_t)zi * sPartc; inv36 += (size_t)zi * sInvc;
  double s = 0.0, q = 0.0;
  for (int b = t; b < NB; b += 256) {
    s += part[(size_t)pos * NB + b];
    q += part[(size_t)(36 + pos) * NB + b];
  }
  for (int off = 32; off; off >>= 1) {
    s += __shfl_down(s, off, 64);
    q += __shfl_down(q, off, 64);
  }
  if ((t & 63) == 0) { sh[(t >> 6) * 2] = s; sh[(t >> 6) * 2 + 1] = q; }
  __syncthreads();
  if (t == 0) {
    s = sh[0] + sh[2] + sh[4] + sh[6];
    q = sh[1] + sh[3] + sh[5] + sh[7];
    double var = (q - s * s / n) / (n - 1.0);
    inv36[pos] = var > 0.0 ? (float)(0.5 / var) : __builtin_inff();
  }
}

// ---------------- L1 GEMM pass B: fused exp/crelu/2x2-alpha-pool epilogue ----------------
__global__ __launch_bounds__(256) void l1_gemm_sfm(
    const u16* __restrict__ Ph, const u16* __restrict__ Pl,
    const u16* __restrict__ W1h, const u16* __restrict__ W1l,
    const float* __restrict__ pnorm, const float* __restrict__ w1n,
    const float* __restrict__ inv36, const float* __restrict__ cb,
    u16* __restrict__ Xhi, u16* __restrict__ Xlo, float* __restrict__ xn,
    int c0, int sPc, int sPnc, int sInvc, int sXc, int sxnc)
{
  __shared__ __align__(16) u16 sm[16384];
  __shared__ float psm[2 * 18 * ESM_P];
  __shared__ float inv_s[36];
  int t = threadIdx.x, zi = blockIdx.y, c = c0 + zi;
  Ph += (size_t)zi * sPc; Pl += (size_t)zi * sPc;
  const u16* Wh = W1h + (size_t)c * 4096;
  const u16* Wl = W1l + (size_t)c * 4096;
  pnorm += (size_t)zi * sPnc;
  const float* wn = w1n + (size_t)c * 128;
  inv36 += (size_t)zi * sInvc;
  Xhi += (size_t)zi * sXc; Xlo += (size_t)zi * sXc; xn += (size_t)zi * sxnc;
  if (t < 36) inv_s[t] = inv36[t];
  f32x4 accv[4][4];
#pragma unroll
  for (int i = 0; i < 4; ++i)
#pragma unroll
    for (int j = 0; j < 4; ++j) accv[i][j] = (f32x4){0.f, 0.f, 0.f, 0.f};
  const int m0 = blockIdx.x * 128;
  L1_MAINLOOP(Ph, Pl, Wh, Wl, m0, sm, accv);

  const float bias = cb[0];
  const int w = t >> 6, lane = t & 63;
  const int wr = w >> 1, wc = w & 1, q4 = lane >> 4, r16 = lane & 15;
#pragma unroll
  for (int i = 0; i < 4; ++i) {
#pragma unroll
    for (int j = 0; j < 4; ++j) {
      int col = wc * 64 + j * 16 + r16;
      float e[4];
#pragma unroll
      for (int r = 0; r < 4; ++r) {
        int pos = i * 16 + q4 * 4 + r;
        float ev = 0.f;
        if (pos < 36) {
          float pn = pnorm[m0 + wr * 64 + pos];
          float d2 = pn + wn[col] - 2.f * accv[i][j][r];
          float d2c = fmaxf(d2, 0.f) + 1e-12f;
          ev = expf(-d2c * inv_s[pos]);
          ev = (ev >= bias) ? ev : 0.f;
        }
        e[r] = ev;
      }
#pragma unroll
      for (int k = 0; k < 2; ++k) {
        int p = i * 8 + q4 * 2 + k;
        if (p < 18) {
          bool top = ((p / 3) & 1) == 0;
          float cc = top ? fmaf(0.729f, e[2 * k], 0.81f * e[2 * k + 1])
                         : fmaf(0.9f, e[2 * k], e[2 * k + 1]);
          psm[(wr * 18 + p) * ESM_P + col] = cc;
        }
      }
    }
  }
  __syncthreads();

  size_t b0 = (size_t)blockIdx.x * 2;
#pragma unroll
  for (int it = 0; it < 5; ++it) {
    int idx = t + 256 * it;
    if (idx >= 1152) break;
    int rowp = idx >> 6;
    int cp = idx & 63;
    int im = rowp / 9, IJ = rowp - im * 9;
    int I = IJ / 3, J = IJ - I * 3;
    const float* basep = &psm[(im * 18 + 6 * I + J) * ESM_P];
    int col0 = 2 * cp, col1 = 2 * cp + 1;
    float v0 = (col0 < 100) ? 0.25f * (basep[col0] + basep[3 * ESM_P + col0]) : 0.f;
    float v1 = (col1 < 100) ? 0.25f * (basep[col1] + basep[3 * ESM_P + col1]) : 0.f;
    u16 h0 = f2bf(v0), h1 = f2bf(v1);
    u16 l0 = f2bf(v0 - bf2f(h0)), l1 = f2bf(v1 - bf2f(h1));
    size_t xrow = b0 * 9 + rowp;
    *(unsigned int*)&Xhi[xrow * 128 + col0] = (unsigned int)h0 | ((unsigned int)h1 << 16);
    *(unsigned int*)&Xlo[xrow * 128 + col0] = (unsigned int)l0 | ((unsigned int)l1 << 16);
    float p = fmaf(v0, v0, v1 * v1);
    for (int off = 32; off; off >>= 1) p += __shfl_down(p, off, 64);
    if ((t & 63) == 0) xn[xrow] = p;
  }
}

// ---------------- split-bf16 MFMA cdist GEMM (L2/L3/L4), fused s/q reduce ----------------
__global__ __launch_bounds__(256) void gemm_dist_mfma(
    const u16* __restrict__ Xhi, const u16* __restrict__ Xlo,
    const u16* __restrict__ Whi, const u16* __restrict__ Wlo,
    const float* __restrict__ xn, const float* __restrict__ wn,
    float* __restrict__ dist, int O, int Kp,
    double* __restrict__ acc, int accbase, int c0,
    int sXc, int sWc, int sxnc, int swnc, int sdistc)
{
  __shared__ __align__(16) u16 sm[4 * 4096];
  __shared__ double redsm[8];
  int zi = blockIdx.z, c = c0 + zi;
  Xhi += (size_t)zi * sXc; Xlo += (size_t)zi * sXc;
  Whi += (size_t)c * sWc;  Wlo += (size_t)c * sWc;
  xn += (size_t)zi * sxnc; wn += (size_t)c * swnc;
  dist += (size_t)zi * sdistc;
  acc += (size_t)c * ACC_TOTAL;

  u16* smAh = sm;
  u16* smAl = sm + 4096;
  u16* smBh = sm + 8192;
  u16* smBl = sm + 12288;

  const int t = threadIdx.x;
  const int w = t >> 6, lane = t & 63;
  const int wr = w >> 1, wc = w & 1;
  const int m0 = blockIdx.x * 128, o0 = blockIdx.y * 128;
  const int q4 = lane >> 4, r16 = lane & 15;

  f32x4 accv[4][4];
#pragma unroll
  for (int i = 0; i < 4; ++i)
#pragma unroll
    for (int j = 0; j < 4; ++j) accv[i][j] = (f32x4){0.f, 0.f, 0.f, 0.f};

  int aoff[4], boff[4];
#pragma unroll
  for (int i = 0; i < 4; ++i) {
    aoff[i] = (q4 * 128 + wr * 64 + i * 16 + r16) * 8;
    boff[i] = (q4 * 128 + wc * 64 + i * 16 + r16) * 8;
  }

  for (int k0 = 0; k0 < Kp; k0 += 32) {
    const int kk = k0 + w * 8;
#pragma unroll
    for (int u = 0; u < 2; ++u) {
      const size_t ga = (size_t)(m0 + u * 64 + lane) * Kp + kk;
      const size_t gb = (size_t)(o0 + u * 64 + lane) * Kp + kk;
      const int ls = (w * 128 + u * 64) * 8;
      gload16(Xhi + ga, smAh + ls);
      gload16(Xlo + ga, smAl + ls);
      gload16(Whi + gb, smBh + ls);
      gload16(Wlo + gb, smBl + ls);
    }
    asm volatile("s_waitcnt vmcnt(0)" ::: "memory");
    __syncthreads();

    bf16x8 Ah[4], Al[4], Bh[4], Bl[4];
#pragma unroll
    for (int i = 0; i < 4; ++i) {
      Ah[i] = *(const bf16x8*)(smAh + aoff[i]);
      Al[i] = *(const bf16x8*)(smAl + aoff[i]);
      Bh[i] = *(const bf16x8*)(smBh + boff[i]);
      Bl[i] = *(const bf16x8*)(smBl + boff[i]);
    }
#pragma unroll
    for (int i = 0; i < 4; ++i)
#pragma unroll
      for (int j = 0; j < 4; ++j) {
        accv[i][j] = __builtin_amdgcn_mfma_f32_16x16x32_bf16(Ah[i], Bh[j], accv[i][j], 0, 0, 0);
        accv[i][j] = __builtin_amdgcn_mfma_f32_16x16x32_bf16(Al[i], Bh[j], accv[i][j], 0, 0, 0);
        accv[i][j] = __builtin_amdgcn_mfma_f32_16x16x32_bf16(Ah[i], Bl[j], accv[i][j], 0, 0, 0);
      }
    __syncthreads();
  }

  double s = 0.0, qd = 0.0;
#pragma unroll
  for (int i = 0; i < 4; ++i) {
    const int mb = m0 + wr * 64 + i * 16 + q4 * 4;
    float xnv[4];
#pragma unroll
    for (int r = 0; r < 4; ++r) xnv[r] = xn[mb + r];
#pragma unroll
    for (int j = 0; j < 4; ++j) {
      const int o = o0 + wc * 64 + j * 16 + r16;
      if (o < O) {
        const float wnv = wn[o];
#pragma unroll
        for (int r = 0; r < 4; ++r) {
          float d2 = xnv[r] + wnv - 2.f * accv[i][j][r];
          float d = sqrtf(fmaxf(d2, 0.f) + 1e-12f);
          dist[(size_t)(mb + r) * O + o] = d;
          s += d; qd += (double)d * d;
        }
      }
    }
  }
  for (int off = 32; off; off >>= 1) {
    s += __shfl_down(s, off, 64);
    qd += __shfl_down(qd, off, 64);
  }
  if (lane == 0) { redsm[w * 2] = s; redsm[w * 2 + 1] = qd; }
  __syncthreads();
  if (t == 0) {
    s = redsm[0] + redsm[2] + redsm[4] + redsm[6];
    qd = redsm[1] + redsm[3] + redsm[5] + redsm[7];
    int stripe = (blockIdx.x + blockIdx.y * gridDim.x) & (STRIPES - 1);
    atomicAdd(&acc[accbase + stripe * 2], s);
    atomicAdd(&acc[accbase + stripe * 2 + 1], qd);
  }
}

// block preamble: reduce 64-stripe acc -> inv = 0.5/var, broadcast via LDS.
// Leading barrier makes repeated calls (fc_acc channel loop) safe.
__device__ __forceinline__ float block_inv_from_acc(
    const double* __restrict__ acc, int base, double n, float* sh)
{
  __syncthreads();
  int t = threadIdx.x;
  if (t < 64) {
    double s = acc[base + 2 * t], q = acc[base + 2 * t + 1];
    for (int off = 32; off; off >>= 1) {
      s += __shfl_down(s, off, 64);
      q += __shfl_down(q, off, 64);
    }
    if (t == 0) {
      double var = (q - s * s / n) / (n - 1.0);
      *sh = var > 0.0 ? (float)(0.5 / var) : __builtin_inff();
    }
  }
  __syncthreads();
  return *sh;
}

// exp -> crelu(cb1) -> [0.81,0.9,1]/3 pool -> hi/lo (Kp=256) + xn
__global__ __launch_bounds__(256) void l2_sfm(
    const float* __restrict__ dist2, const double* __restrict__ acc, double n,
    const float* __restrict__ cb, u16* __restrict__ Xhi, u16* __restrict__ Xlo,
    float* __restrict__ xn, int c0, int sdistc, int sXc, int sxnc)
{
  __shared__ float shinv;
  __shared__ float red[4];
  int zi = blockIdx.z, c = c0 + zi;
  dist2 += (size_t)zi * sdistc;
  Xhi += (size_t)zi * sXc; Xlo += (size_t)zi * sXc; xn += (size_t)zi * sxnc;
  float inv = block_inv_from_acc(acc + (size_t)c * ACC_TOTAL, ACC_L2, n, &shinv);
  int b = blockIdx.x, u = blockIdx.y, ch = threadIdx.x;
  float bias = cb[1];
  float v = 0.f;
  if (ch < 225) {
    const float av[3] = {0.81f, 0.9f, 1.0f};
    float a = 0.f;
#pragma unroll
    for (int vv = 0; vv < 3; ++vv) {
      float d = dist2[((size_t)b * 9 + u * 3 + vv) * 225 + ch];
      float e = expf(-d * d * inv);
      e = (e >= bias) ? e : 0.f;
      a = fmaf(e, av[vv], a);
    }
    v = a * (1.f / 3.f);
  }
  size_t row = (size_t)b * 3 + u;
  u16 h = f2bf(v);
  u16 l = f2bf(v - bf2f(h));
  Xhi[row * 256 + ch] = h;
  Xlo[row * 256 + ch] = l;
  float p = v * v;
  for (int off = 32; off; off >>= 1) p += __shfl_down(p, off, 64);
  if ((ch & 63) == 0) red[ch >> 6] = p;
  __syncthreads();
  if (ch == 0) xn[row] = red[0] + red[1] + red[2] + red[3];
}

// exp -> crelu(cb2) -> [0.81,0.9,1]/3 pool -> hi/lo (Kp=640) + xn
__global__ __launch_bounds__(256) void l3_sfm(
    const float* __restrict__ dist3, const double* __restrict__ acc, double n,
    const float* __restrict__ cb, u16* __restrict__ Xhi, u16* __restrict__ Xlo,
    float* __restrict__ xn, int c0, int sdistc, int sXc, int sxnc)
{
  __shared__ float shinv;
  __shared__ float red[4];
  int zi = blockIdx.y, c = c0 + zi;
  dist3 += (size_t)zi * sdistc;
  Xhi += (size_t)zi * sXc; Xlo += (size_t)zi * sXc; xn += (size_t)zi * sxnc;
  float inv = block_inv_from_acc(acc + (size_t)c * ACC_TOTAL, ACC_L3, n, &shinv);
  int b = blockIdx.x, t = threadIdx.x;
  float bias = cb[2];
  const float au[3] = {0.81f, 0.9f, 1.0f};
  float p = 0.f;
  for (int ch = t; ch < 640; ch += 256) {
    float v = 0.f;
    if (ch < 625) {
      float a = 0.f;
#pragma unroll
      for (int u = 0; u < 3; ++u) {
        float d = dist3[((size_t)b * 3 + u) * 625 + ch];
        float e = expf(-d * d * inv);
        e = (e >= bias) ? e : 0.f;
        a = fmaf(e, au[u], a);
      }
      v = a * (1.f / 3.f);
    }
    u16 h = f2bf(v);
    u16 l = f2bf(v - bf2f(h));
    Xhi[(size_t)b * 640 + ch] = h;
    Xlo[(size_t)b * 640 + ch] = l;
    p = fmaf(v, v, p);
  }
  for (int off = 32; off; off >>= 1) p += __shfl_down(p, off, 64);
  if ((t & 63) == 0) red[t >> 6] = p;
  __syncthreads();
  if (t == 0) xn[b] = red[0] + red[1] + red[2] + red[3];
}

// L4 exp/crelu fused into FC; loops nc channels internally (no atomics)
__global__ __launch_bounds__(128) void fc_acc(
    const float* __restrict__ dist4, const double* __restrict__ acc, double n,
    const float* __restrict__ cb, const float* __restrict__ fcw,
    const float* __restrict__ fcb, float* __restrict__ out,
    int c0, int nc, int sdistc)
{
  __shared__ float shinv;
  int b = blockIdx.x, t = threadIdx.x;
  float bias = cb[3];
  float p[10];
#pragma unroll
  for (int k = 0; k < 10; ++k) p[k] = 0.f;
  for (int zi = 0; zi < nc; ++zi) {
    int c = c0 + zi;
    float inv = block_inv_from_acc(acc + (size_t)c * ACC_TOTAL, ACC_L4, n, &shinv);
    const float* d4 = dist4 + (size_t)zi * sdistc;
    for (int j = t; j < 1225; j += 128) {
      float d = d4[(size_t)b * 1225 + j];
      float v = expf(-d * d * inv);
      v = (v >= bias) ? v : 0.f;
#pragma unroll
      for (int k = 0; k < 10; ++k) p[k] = fmaf(v, fcw[k * 3675 + c * 1225 + j], p[k]);
    }
  }
#pragma unroll
  for (int k = 0; k < 10; ++k)
    for (int off = 32; off; off >>= 1) p[k] += __shfl_down(p[k], off, 64);
  __shared__ float red[2][10];
  int wave = t >> 6;
  if ((t & 63) == 0) {
#pragma unroll
    for (int k = 0; k < 10; ++k) red[wave][k] = p[k];
  }
  __syncthreads();
  if (t < 10) {
    float v = red[0][t] + red[1][t];
    if (c0 == 0) out[(size_t)b * 10 + t] = fcb[t] + v;
    else         out[(size_t)b * 10 + t] += v;
  }
}

extern "C" void kernel_launch(void* const* d_in, const int* in_sizes, int n_in,
                              void* d_out, int out_size, void* d_ws, size_t ws_size,
                              hipStream_t stream) {
  const float* x   = (const float*)d_in[0];
  const float* w1  = (const float*)d_in[1];
  const float* w2  = (const float*)d_in[2];
  const float* w3  = (const float*)d_in[3];
  const float* w4  = (const float*)d_in[4];
  const float* fcw = (const float*)d_in[5];
  const float* fcb = (const float*)d_in[6];
  const float* cb  = (const float*)d_in[7];
  float* out = (float*)d_out;
  const int B = in_sizes[0] / (3 * 28 * 28);   // 4096
  const int M2 = B * 9, M3 = B * 3;
  const int NB = B / 2;

  // layout: try batched (plan A); fall back to serial (plan B) if ws too small
  bool batched = true;
  u16 *Ph, *Pl, *Xbase, *Whi, *Wlo, *W1h, *W1l;
  float *wn, *w1n, *pnorm, *xn, *inv36, *part;
  double* accd;
  float* Sf;                 // scratch region as float (dist buffers)
  for (int attempt = 0; attempt < 2; ++attempt) {
    size_t cur = 0;
    char* basep = (char*)d_ws;
    auto take = [&](size_t bytes) {
      void* r = basep + cur;
      cur = (cur + bytes + 255) & ~(size_t)255;
      return r;
    };
    int nc = batched ? 3 : 1;
    size_t Psz = (size_t)B * 64 * 32 * 2 * 2;                 // hi+lo per channel
    size_t Ssz = Psz * nc;
    size_t d2sz = (size_t)M2 * 225 * 4 * nc;
    if (d2sz > Ssz) Ssz = d2sz;
    Sf = (float*)take(Ssz);
    Ph = (u16*)Sf;  Pl = Ph + (size_t)B * 64 * 32;
    Xbase = (u16*)take((size_t)M2 * 128 * 2 * 2 * nc);
    Whi = (u16*)take(3047424 * 2); Wlo = (u16*)take(3047424 * 2);
    W1h = (u16*)take(12288 * 2);   W1l = (u16*)take(12288 * 2);
    wn  = (float*)take(6528 * 4);  w1n = (float*)take(384 * 4);
    pnorm = (float*)take((size_t)B * 64 * 4 * nc);
    xn    = (float*)take((size_t)M2 * 4 * nc);
    inv36 = (float*)take(40 * 4 * nc);
    part  = (float*)take((size_t)72 * NB * 4 * nc);
    accd  = (double*)take(3 * ACC_TOTAL * 8);
    if (cur <= ws_size) break;
    batched = false;
  }
  const int nc = batched ? 3 : 1;

  // per-channel scratch strides (elements); 0 in serial plan (buffers reused)
  const int sPc    = batched ? B * 64 * 32 * 2 : 0;   // u16 (hi+lo block)
  const int sPnc   = batched ? B * 64 : 0;
  const int sPartc = batched ? 72 * NB : 0;
  const int sInvc  = batched ? 40 : 0;
  const int sX2c   = batched ? M2 * 128 * 2 : 0;      // u16 (hi+lo block)
  const int sX3c   = batched ? M3 * 256 * 2 : 0;
  const int sX4c   = batched ? B * 640 * 2 : 0;
  const int sD2c   = batched ? M2 * 225 : 0;          // floats
  const int sD3c   = batched ? M3 * 625 : 0;
  const int sD4c   = batched ? B * 1225 : 0;
  const int sXn2c  = batched ? M2 : 0;
  const int sXn3c  = batched ? M3 : 0;
  const int sXn4c  = batched ? B : 0;

  u16* x2hi = Xbase;                u16* x2lo = Xbase + (size_t)M2 * 128;
  u16* x3hi = Xbase;                u16* x3lo = Xbase + (size_t)M3 * 256;
  u16* x4hi = Xbase;                u16* x4lo = Xbase + (size_t)B * 640;
  u16* Whi2 = Whi;           u16* Wlo2 = Wlo;           float* wn2 = wn;
  u16* Whi3 = Whi + 98304;   u16* Wlo3 = Wlo + 98304;   float* wn3 = wn + 768;
  u16* Whi4 = Whi + 589824;  u16* Wlo4 = Wlo + 589824;  float* wn4 = wn + 2688;

  zero_acc_kernel<<<(3 * ACC_TOTAL + 255) / 256, 256, 0, stream>>>(accd, 3 * ACC_TOTAL);
  w_prep<<<dim3(128, 3),  128, 0, stream>>>(w1, 100, 25,  128, 32,  W1h,  W1l,  w1n);
  w_prep<<<dim3(256, 3),  128, 0, stream>>>(w2, 225, 100, 256, 128, Whi2, Wlo2, wn2);
  w_prep<<<dim3(640, 3),  128, 0, stream>>>(w3, 625, 225, 640, 256, Whi3, Wlo3, wn3);
  w_prep<<<dim3(1280, 3), 128, 0, stream>>>(w4, 1225, 625, 1280, 640, Whi4, Wlo4, wn4);

  for (int c0 = 0; c0 < 3; c0 += nc) {
    // L1 (MFMA two-pass)
    l1_extract<<<dim3(B, nc), 128, 0, stream>>>(x, c0, Ph, Pl, pnorm, sPc, sPnc);
    l1_gemm_reduce<<<dim3(NB, nc), 256, 0, stream>>>(
        Ph, Pl, W1h, W1l, pnorm, w1n, part, NB, c0, sPc, sPnc, sPartc);
    l1_part_fin<<<dim3(36, nc), 256, 0, stream>>>(part, NB, inv36, (double)B * 100.0,
                                                  sPartc, sInvc);
    l1_gemm_sfm<<<dim3(NB, nc), 256, 0, stream>>>(
        Ph, Pl, W1h, W1l, pnorm, w1n, inv36, cb, x2hi, x2lo, xn,
        c0, sPc, sPnc, sInvc, sX2c, sXn2c);

    // L2: (M2 x 128) x (256 x 128) -> dist2 (M2 x 225)
    gemm_dist_mfma<<<dim3(M2 / 128, 2, nc), 256, 0, stream>>>(
        x2hi, x2lo, Whi2, Wlo2, xn, wn2, Sf, 225, 128, accd, ACC_L2, c0,
        sX2c, 256 * 128, sXn2c, 256, sD2c);
    l2_sfm<<<dim3(B, 3, nc), 256, 0, stream>>>(
        Sf, accd, (double)M2 * 225.0, cb, x3hi, x3lo, xn, c0, sD2c, sX3c, sXn3c);

    // L3: (M3 x 256) x (640 x 256) -> dist3 (M3 x 625)
    gemm_dist_mfma<<<dim3(M3 / 128, 5, nc), 256, 0, stream>>>(
        x3hi, x3lo, Whi3, Wlo3, xn, wn3, Sf, 625, 256, accd, ACC_L3, c0,
        sX3c, 640 * 256, sXn3c, 640, sD3c);
    l3_sfm<<<dim3(B, nc), 256, 0, stream>>>(
        Sf, accd, (double)M3 * 625.0, cb, x4hi, x4lo, xn, c0, sD3c, sX4c, sXn4c);

    // L4: (B x 640) x (1280 x 640) -> dist4 (B x 1225)
    gemm_dist_mfma<<<dim3(B / 128, 10, nc), 256, 0, stream>>>(
        x4hi, x4lo, Whi4, Wlo4, xn, wn4, Sf, 1225, 640, accd, ACC_L4, c0,
        sX4c, 1280 * 640, sXn4c, 1280, sD4c);
    fc_acc<<<B, 128, 0, stream>>>(
        Sf, accd, (double)B * 1225.0, cb, fcw, fcb, out, c0, nc, sD4c);
  }
}